// Round 7
// baseline (331.923 us; speedup 1.0000x reference)
//
#include <hip/hip_runtime.h>
#include <stdint.h>

typedef unsigned short u16;
typedef __attribute__((ext_vector_type(8))) __bf16 bf16x8;
typedef __attribute__((ext_vector_type(4))) __bf16 bf16x4v;
typedef __attribute__((ext_vector_type(4))) float f32x4;
typedef __attribute__((ext_vector_type(4))) unsigned short u16x4;

#define MFMA16(a,b,c) __builtin_amdgcn_mfma_f32_16x16x32_bf16(a,b,c,0,0,0)

// hardware v_exp_f32 (2^x) — precise libm exp2f costs ~15 VALU instrs
static __device__ __forceinline__ float fexp2(float x){
#if __has_builtin(__builtin_amdgcn_exp2f)
  return __builtin_amdgcn_exp2f(x);
#else
  float r; asm("v_exp_f32 %0, %1" : "=v"(r) : "v"(x)); return r;
#endif
}

// f32 -> bf16 bits, round-to-nearest-even
static __device__ __forceinline__ u16 f2b(float f){
  uint32_t u = __float_as_uint(f);
  u += 0x7fffu + ((u >> 16) & 1u);
  return (u16)(u >> 16);
}

static __device__ __forceinline__ void gload_lds16(const void* g, void* l){
  __builtin_amdgcn_global_load_lds(
      (__attribute__((address_space(1))) void*)(uintptr_t)g,
      (__attribute__((address_space(3))) void*)(uintptr_t)l,
      16, 0, 0);
}

// ---------------- fp32 -> bf16 elementwise ----------------
__global__ __launch_bounds__(256) void cvt_bf16(const float* __restrict__ in,
                                                u16* __restrict__ out, int n){
  int i = (blockIdx.x * 256 + threadIdx.x) * 4;
  if (i >= n) return;
  float4 v = *(const float4*)(in + i);
  u16x4 o;
  o.x = f2b(v.x); o.y = f2b(v.y); o.z = f2b(v.z); o.w = f2b(v.w);
  *(u16x4*)(out + i) = o;
}

// ---------------- transpose+convert: in[K][N] f32 -> out[N][K] bf16 ----------------
__global__ __launch_bounds__(256) void transpose_cvt(const float* __restrict__ in,
                                                     u16* __restrict__ out,
                                                     int K, int N){
  __shared__ float tile[32][33];
  const int nb = blockIdx.x * 32, kb = blockIdx.y * 32;
  const int tx = threadIdx.x, ty = threadIdx.y; // (32,8)
#pragma unroll
  for (int i = 0; i < 32; i += 8)
    tile[ty + i][tx] = in[(size_t)(kb + ty + i) * N + nb + tx];
  __syncthreads();
#pragma unroll
  for (int i = 0; i < 32; i += 8)
    out[(size_t)(nb + ty + i) * K + kb + tx] = f2b(tile[tx][ty + i]);
}

// ---------------- bf16 GEMM: C[M,N] = A[M,K] * Bt[N,K]^T + bias ----------------
template<int MODE>
__global__ __launch_bounds__(256) void gemm_bf16(
    const u16* __restrict__ A, const u16* __restrict__ Bt,
    const float* __restrict__ bias, float* __restrict__ Cout,
    u16* __restrict__ q_bf, u16* __restrict__ k_bf, u16* __restrict__ vT_bf,
    int M, int N, int K)
{
  __shared__ u16 As[128 * 64];
  __shared__ u16 Bs[128 * 64];
  const int tid = threadIdx.x;
  const int w = tid >> 6, lane = tid & 63;
  const int l15 = lane & 15, lhi = lane >> 4;
  const int mBase = blockIdx.y * 128, nBase = blockIdx.x * 128;
  const int wr = w >> 1, wc = w & 1;

  f32x4 acc[4][4];
#pragma unroll
  for (int i = 0; i < 4; ++i)
#pragma unroll
    for (int j = 0; j < 4; ++j) acc[i][j] = f32x4{0.f, 0.f, 0.f, 0.f};

  const int nK = K >> 6;
  for (int kt = 0; kt < nK; ++kt){
    const int kb = kt << 6;
#pragma unroll
    for (int i = 0; i < 4; ++i){
      const int idx = i * 256 + tid;
      const int row = idx >> 3, c8 = idx & 7;
      gload_lds16(A  + (size_t)(mBase + row) * K + kb + c8 * 8,
                  As + (size_t)(i * 256 + w * 64) * 8);
      gload_lds16(Bt + (size_t)(nBase + row) * K + kb + c8 * 8,
                  Bs + (size_t)(i * 256 + w * 64) * 8);
    }
    __syncthreads();
#pragma unroll
    for (int kk = 0; kk < 2; ++kk){
      bf16x8 af[4], bb[4];
#pragma unroll
      for (int mi = 0; mi < 4; ++mi)
        af[mi] = *(const bf16x8*)&As[(wr * 64 + mi * 16 + l15) * 64 + kk * 32 + lhi * 8];
#pragma unroll
      for (int ni = 0; ni < 4; ++ni)
        bb[ni] = *(const bf16x8*)&Bs[(wc * 64 + ni * 16 + l15) * 64 + kk * 32 + lhi * 8];
#pragma unroll
      for (int mi = 0; mi < 4; ++mi)
#pragma unroll
        for (int ni = 0; ni < 4; ++ni)
          acc[mi][ni] = MFMA16(af[mi], bb[ni], acc[mi][ni]);
    }
    __syncthreads();
  }

  // epilogue
#pragma unroll
  for (int ni = 0; ni < 4; ++ni){
    const int col = nBase + wc * 64 + ni * 16 + l15;
    const float bv = bias[col];
#pragma unroll
    for (int mi = 0; mi < 4; ++mi){
#pragma unroll
      for (int r = 0; r < 4; ++r){
        const int row = mBase + wr * 64 + mi * 16 + lhi * 4 + r;
        const float v = acc[mi][ni][r] + bv;
        if (MODE == 0){
          Cout[(size_t)row * N + col] = v;
        } else {
          const int b = row >> 11, s = row & 2047;
          const int sec = col >> 10, nn = col & 1023;
          const int h = nn >> 6, d = nn & 63;
          const size_t bhsd = ((size_t)(b * 16 + h) * 2048 + s) * 64 + d;
          if (sec == 0){
            q_bf[bhsd] = f2b(v * 0.1803368801111204f);      // 1/8 * log2(e)
          } else if (sec == 1){
            k_bf[bhsd] = f2b(v);
            Cout[8388608 + bhsd] = v;                       // present[0] = k
          } else {
            vT_bf[((size_t)(b * 16 + h) * 64 + d) * 2048 + s] = f2b(v);
            Cout[16777216 + bhsd] = v;                      // present[1] = v
          }
        }
      }
    }
  }
}

// ---------------- causal flash attention ----------------
// grid (16,64) = 1024 blocks, 4 waves each -> 4096 waves = 16 waves/CU.
// Each wave: 16 rows of LONG tile (31-bx) + 16 rows of SHORT tile (bx),
// sharing one K/V fetch per KV-block; short tile predicated off when
// it >= nB (wave-uniform). XCD remap keeps each head's blocks on one XCD.
// Swapped QK^T (mfma(K,Q)): lane holds 16 scores of ONE q-row -> softmax =
// in-lane tree + 2 shfl_xor. Defer-max (THR=8, exp2 domain); hw v_exp_f32.
__global__ __launch_bounds__(256) void attn_kern(
    const u16* __restrict__ q_bf, const u16* __restrict__ k_bf,
    const u16* __restrict__ vT_bf, u16* __restrict__ a_bf)
{
  const int S = 2048;
  // ---- XCD-locality block remap (bijective on [0,1024)) ----
  const int id = (int)blockIdx.x + 16 * (int)blockIdx.y;
  const int xcd = id & 7, j = id >> 3;
  const int bh = xcd + 8 * (j & 7);   // all 16 blocks of a head share id%8
  const int bx = j >> 3;              // 0..15

  const int tid = threadIdx.x, w = tid >> 6, lane = tid & 63;
  const int l15 = lane & 15, lhi = lane >> 4;
  const u16* qp = q_bf + (size_t)bh * S * 64;
  const u16* kp = k_bf + (size_t)bh * S * 64;
  const u16* vp = vT_bf + (size_t)bh * 64 * S;
  const int b = bh >> 4, h = bh & 15;

  __shared__ u16 P_all[4][32 * 64];
  char* Pc = (char*)&P_all[w][0];
  const int swz = (l15 & 7) << 4;

  const int qtA = 31 - bx, qtB = bx;
  const int nA = qtA + 1, nB = qtB + 1;          // KV-block counts (nA >= 17 > nB)
  const int qr0A = qtA * 64 + w * 16;
  const int qr0B = qtB * 64 + w * 16;

  bf16x8 qfA[2], qfB[2];
  qfA[0] = *(const bf16x8*)&qp[(qr0A + l15) * 64 + lhi * 8];
  qfA[1] = *(const bf16x8*)&qp[(qr0A + l15) * 64 + 32 + lhi * 8];
  qfB[0] = *(const bf16x8*)&qp[(qr0B + l15) * 64 + lhi * 8];
  qfB[1] = *(const bf16x8*)&qp[(qr0B + l15) * 64 + 32 + lhi * 8];

  f32x4 oA[4], oB[4];
#pragma unroll
  for (int df = 0; df < 4; ++df){ oA[df] = f32x4{0.f,0.f,0.f,0.f}; oB[df] = f32x4{0.f,0.f,0.f,0.f}; }
  float mA = -1e30f, lA = 0.f, mB = -1e30f, lB = 0.f;

  // per-group softmax + P-pack + PV (gofs selects this group's 2KB of P)
  auto process = [&](f32x4 (&s)[4], float &m, float &l, f32x4 (&o)[4],
                     const bf16x8 (&vf)[8], int qr0, bool domask, int jb, int gofs){
    if (domask){
      const int q = qr0 + l15;
#pragma unroll
      for (int nf = 0; nf < 4; ++nf)
#pragma unroll
        for (int r = 0; r < 4; ++r){
          const int kv = jb + nf * 16 + lhi * 4 + r;
          if (kv > q) s[nf][r] = -1e10f;
        }
    }
    // row max: balanced tree (fuses to v_max3) + 2 cross-lane
    float a0 = fmaxf(s[0][0], s[0][1]), a1 = fmaxf(s[0][2], s[0][3]);
    float a2 = fmaxf(s[1][0], s[1][1]), a3 = fmaxf(s[1][2], s[1][3]);
    float a4 = fmaxf(s[2][0], s[2][1]), a5 = fmaxf(s[2][2], s[2][3]);
    float a6 = fmaxf(s[3][0], s[3][1]), a7 = fmaxf(s[3][2], s[3][3]);
    float x = fmaxf(fmaxf(fmaxf(a0,a1), fmaxf(a2,a3)),
                    fmaxf(fmaxf(a4,a5), fmaxf(a6,a7)));
    x = fmaxf(x, __shfl_xor(x, 16));
    x = fmaxf(x, __shfl_xor(x, 32));
    // defer-max: rescale only when running max grew by > 8 (2^8 headroom)
    if (__any(x - m > 8.0f)){
      const float mn = fmaxf(m, x);
      const float sc = fexp2(m - mn);
      m = mn;
      l *= sc;
      float scq[4];
#pragma unroll
      for (int r = 0; r < 4; ++r)
        scq[r] = __shfl(sc, (lane & 48) | (lhi * 4 + r));
#pragma unroll
      for (int df = 0; df < 4; ++df)
#pragma unroll
        for (int r = 0; r < 4; ++r) o[df][r] *= scq[r];
    }
    // p = 2^(s-m) via v_exp_f32; sum as balanced tree + 2 cross-lane
    float p[16];
#pragma unroll
    for (int nf = 0; nf < 4; ++nf)
#pragma unroll
      for (int r = 0; r < 4; ++r) p[nf*4+r] = fexp2(s[nf][r] - m);
    float rs = (((p[0]+p[1])+(p[2]+p[3])) + ((p[4]+p[5])+(p[6]+p[7])))
             + (((p[8]+p[9])+(p[10]+p[11])) + ((p[12]+p[13])+(p[14]+p[15])));
    rs += __shfl_xor(rs, 16);
    rs += __shfl_xor(rs, 32);
    l += rs;
    // P[q][kv] -> LDS, native v_cvt_pk_bf16_f32 packs, b64 writes, XOR-swizzled
#pragma unroll
    for (int nf = 0; nf < 4; ++nf){
      bf16x4v pk;
#pragma unroll
      for (int r = 0; r < 4; ++r) pk[r] = (__bf16)p[nf*4+r];
      *(bf16x4v*)(Pc + gofs + ((l15 * 128 + nf * 32 + lhi * 8) ^ swz)) = pk;
    }
    // PV
    __builtin_amdgcn_s_setprio(1);
#pragma unroll
    for (int kk = 0; kk < 2; ++kk){
      const bf16x8 pa = *(const bf16x8*)(Pc + gofs + ((l15 * 128 + kk * 64 + lhi * 16) ^ swz));
#pragma unroll
      for (int df = 0; df < 4; ++df)
        o[df] = MFMA16(pa, vf[kk*4+df], o[df]);
    }
    __builtin_amdgcn_s_setprio(0);
  };

  // preload K fragments for jb = 0
  bf16x8 kf[8];
#pragma unroll
  for (int nf = 0; nf < 4; ++nf){
    kf[2*nf]   = *(const bf16x8*)&kp[(nf * 16 + l15) * 64 + lhi * 8];
    kf[2*nf+1] = *(const bf16x8*)&kp[(nf * 16 + l15) * 64 + 32 + lhi * 8];
  }

  for (int it = 0; it < nA; ++it){
    const int jb = it * 64;
    const bool doB = (it < nB);
    // V fragments (shared by both groups; latency hides under QK + softmax)
    bf16x8 vf[8];
#pragma unroll
    for (int kk = 0; kk < 2; ++kk)
#pragma unroll
      for (int df = 0; df < 4; ++df)
        vf[kk*4+df] = *(const bf16x8*)&vp[((size_t)(df * 16 + l15)) * S + jb + kk * 32 + lhi * 8];
    // QK^T swapped: s = K_tile * Q  ->  q-col = l15, kv = nf*16 + lhi*4 + r
    f32x4 sA[4], sB[4];
    __builtin_amdgcn_s_setprio(1);
#pragma unroll
    for (int nf = 0; nf < 4; ++nf){
      f32x4 z = {0.f, 0.f, 0.f, 0.f};
      z = MFMA16(kf[2*nf], qfA[0], z);
      z = MFMA16(kf[2*nf+1], qfA[1], z);
      sA[nf] = z;
    }
    if (doB){
#pragma unroll
      for (int nf = 0; nf < 4; ++nf){
        f32x4 z = {0.f, 0.f, 0.f, 0.f};
        z = MFMA16(kf[2*nf], qfB[0], z);
        z = MFMA16(kf[2*nf+1], qfB[1], z);
        sB[nf] = z;
      }
    }
    __builtin_amdgcn_s_setprio(0);
    // load next-iteration K straight into kf (just consumed by QK MFMAs)
    const int jn = (it + 1 < nA) ? (jb + 64) : 0;
#pragma unroll
    for (int nf = 0; nf < 4; ++nf){
      kf[2*nf]   = *(const bf16x8*)&kp[(jn + nf * 16 + l15) * 64 + lhi * 8];
      kf[2*nf+1] = *(const bf16x8*)&kp[(jn + nf * 16 + l15) * 64 + 32 + lhi * 8];
    }

    process(sA, mA, lA, oA, vf, qr0A, it == nA - 1, jb, 0);
    if (doB)
      process(sB, mB, lB, oB, vf, qr0B, it == nB - 1, jb, 2048);
  }

  // finalize both groups: broadcast 1/l per q-row, store a[b][s][h*64+d]
  auto finalize = [&](float l, f32x4 (&o)[4], int qr0){
    const float linv = 1.0f / l;
    float lr[4];
#pragma unroll
    for (int r = 0; r < 4; ++r)
      lr[r] = __shfl(linv, (lane & 48) | (lhi * 4 + r));
#pragma unroll
    for (int r = 0; r < 4; ++r){
      const int qrow = qr0 + lhi * 4 + r;
#pragma unroll
      for (int df = 0; df < 4; ++df)
        a_bf[((size_t)b * 2048 + qrow) * 1024 + h * 64 + df * 16 + l15] = f2b(o[df][r] * lr[r]);
    }
  };
  finalize(lA, oA, qr0A);
  finalize(lB, oB, qr0B);
}

extern "C" void kernel_launch(void* const* d_in, const int* in_sizes, int n_in,
                              void* d_out, int out_size, void* d_ws, size_t ws_size,
                              hipStream_t stream)
{
  const float* x      = (const float*)d_in[0];
  const float* w_attn = (const float*)d_in[1];
  const float* b_attn = (const float*)d_in[2];
  const float* w_proj = (const float*)d_in[3];
  const float* b_proj = (const float*)d_in[4];
  float* out = (float*)d_out;
  char* ws = (char*)d_ws;
  const size_t MB = 1u << 20;
  u16* x_bf  = (u16*)(ws + 0);        // 16 MB, reused as a_bf after attention
  u16* wA_T  = (u16*)(ws + 16 * MB);  // 6 MB
  u16* wP_T  = (u16*)(ws + 22 * MB);  // 2 MB
  u16* q_bf  = (u16*)(ws + 24 * MB);  // 16 MB
  u16* k_bf  = (u16*)(ws + 40 * MB);  // 16 MB
  u16* vT_bf = (u16*)(ws + 56 * MB);  // 16 MB
  u16* a_bf  = x_bf;

  cvt_bf16<<<dim3(8192), dim3(256), 0, stream>>>(x, x_bf, 4 * 2048 * 1024);
  transpose_cvt<<<dim3(96, 32), dim3(32, 8), 0, stream>>>(w_attn, wA_T, 1024, 3072);
  transpose_cvt<<<dim3(32, 32), dim3(32, 8), 0, stream>>>(w_proj, wP_T, 1024, 1024);
  gemm_bf16<1><<<dim3(24, 64), dim3(256), 0, stream>>>(
      x_bf, wA_T, b_attn, out, q_bf, k_bf, vT_bf, 8192, 3072, 1024);
  attn_kern<<<dim3(16, 64), dim3(256), 0, stream>>>(q_bf, k_bf, vT_bf, a_bf);
  gemm_bf16<0><<<dim3(8, 64), dim3(256), 0, stream>>>(
      a_bf, wP_T, b_proj, out, nullptr, nullptr, nullptr, 8192, 1024, 1024);
}

// Round 8
// 224.772 us; speedup vs baseline: 1.4767x; 1.4767x over previous
//
#include <hip/hip_runtime.h>
#include <stdint.h>

typedef unsigned short u16;
typedef __attribute__((ext_vector_type(8))) __bf16 bf16x8;
typedef __attribute__((ext_vector_type(4))) __bf16 bf16x4v;
typedef __attribute__((ext_vector_type(4))) float f32x4;
typedef __attribute__((ext_vector_type(4))) unsigned short u16x4;

#define MFMA16(a,b,c) __builtin_amdgcn_mfma_f32_16x16x32_bf16(a,b,c,0,0,0)

// hardware v_exp_f32 (2^x)
static __device__ __forceinline__ float fexp2(float x){
#if __has_builtin(__builtin_amdgcn_exp2f)
  return __builtin_amdgcn_exp2f(x);
#else
  float r; asm("v_exp_f32 %0, %1" : "=v"(r) : "v"(x)); return r;
#endif
}

// f32 -> bf16 bits, round-to-nearest-even
static __device__ __forceinline__ u16 f2b(float f){
  uint32_t u = __float_as_uint(f);
  u += 0x7fffu + ((u >> 16) & 1u);
  return (u16)(u >> 16);
}

static __device__ __forceinline__ void gload_lds16(const void* g, void* l){
  __builtin_amdgcn_global_load_lds(
      (__attribute__((address_space(1))) void*)(uintptr_t)g,
      (__attribute__((address_space(3))) void*)(uintptr_t)l,
      16, 0, 0);
}

// ---------------- fp32 -> bf16 elementwise ----------------
__global__ __launch_bounds__(256) void cvt_bf16(const float* __restrict__ in,
                                                u16* __restrict__ out, int n){
  int i = (blockIdx.x * 256 + threadIdx.x) * 4;
  if (i >= n) return;
  float4 v = *(const float4*)(in + i);
  u16x4 o;
  o.x = f2b(v.x); o.y = f2b(v.y); o.z = f2b(v.z); o.w = f2b(v.w);
  *(u16x4*)(out + i) = o;
}

// ---------------- transpose+convert: in[K][N] f32 -> out[N][K] bf16 ----------------
__global__ __launch_bounds__(256) void transpose_cvt(const float* __restrict__ in,
                                                     u16* __restrict__ out,
                                                     int K, int N){
  __shared__ float tile[32][33];
  const int nb = blockIdx.x * 32, kb = blockIdx.y * 32;
  const int tx = threadIdx.x, ty = threadIdx.y; // (32,8)
#pragma unroll
  for (int i = 0; i < 32; i += 8)
    tile[ty + i][tx] = in[(size_t)(kb + ty + i) * N + nb + tx];
  __syncthreads();
#pragma unroll
  for (int i = 0; i < 32; i += 8)
    out[(size_t)(nb + ty + i) * K + kb + tx] = f2b(tile[tx][ty + i]);
}

// ---------------- bf16 GEMM: C[M,N] = A[M,K] * Bt[N,K]^T + bias ----------------
template<int MODE>
__global__ __launch_bounds__(256) void gemm_bf16(
    const u16* __restrict__ A, const u16* __restrict__ Bt,
    const float* __restrict__ bias, float* __restrict__ Cout,
    u16* __restrict__ q_bf, u16* __restrict__ k_bf, u16* __restrict__ vT_bf,
    int M, int N, int K)
{
  __shared__ u16 As[128 * 64];
  __shared__ u16 Bs[128 * 64];
  const int tid = threadIdx.x;
  const int w = tid >> 6, lane = tid & 63;
  const int l15 = lane & 15, lhi = lane >> 4;
  const int mBase = blockIdx.y * 128, nBase = blockIdx.x * 128;
  const int wr = w >> 1, wc = w & 1;

  f32x4 acc[4][4];
#pragma unroll
  for (int i = 0; i < 4; ++i)
#pragma unroll
    for (int j = 0; j < 4; ++j) acc[i][j] = f32x4{0.f, 0.f, 0.f, 0.f};

  const int nK = K >> 6;
  for (int kt = 0; kt < nK; ++kt){
    const int kb = kt << 6;
#pragma unroll
    for (int i = 0; i < 4; ++i){
      const int idx = i * 256 + tid;
      const int row = idx >> 3, c8 = idx & 7;
      gload_lds16(A  + (size_t)(mBase + row) * K + kb + c8 * 8,
                  As + (size_t)(i * 256 + w * 64) * 8);
      gload_lds16(Bt + (size_t)(nBase + row) * K + kb + c8 * 8,
                  Bs + (size_t)(i * 256 + w * 64) * 8);
    }
    __syncthreads();
#pragma unroll
    for (int kk = 0; kk < 2; ++kk){
      bf16x8 af[4], bb[4];
#pragma unroll
      for (int mi = 0; mi < 4; ++mi)
        af[mi] = *(const bf16x8*)&As[(wr * 64 + mi * 16 + l15) * 64 + kk * 32 + lhi * 8];
#pragma unroll
      for (int ni = 0; ni < 4; ++ni)
        bb[ni] = *(const bf16x8*)&Bs[(wc * 64 + ni * 16 + l15) * 64 + kk * 32 + lhi * 8];
#pragma unroll
      for (int mi = 0; mi < 4; ++mi)
#pragma unroll
        for (int ni = 0; ni < 4; ++ni)
          acc[mi][ni] = MFMA16(af[mi], bb[ni], acc[mi][ni]);
    }
    __syncthreads();
  }

  // epilogue
#pragma unroll
  for (int ni = 0; ni < 4; ++ni){
    const int col = nBase + wc * 64 + ni * 16 + l15;
    const float bv = bias[col];
#pragma unroll
    for (int mi = 0; mi < 4; ++mi){
#pragma unroll
      for (int r = 0; r < 4; ++r){
        const int row = mBase + wr * 64 + mi * 16 + lhi * 4 + r;
        const float v = acc[mi][ni][r] + bv;
        if (MODE == 0){
          Cout[(size_t)row * N + col] = v;
        } else {
          const int b = row >> 11, s = row & 2047;
          const int sec = col >> 10, nn = col & 1023;
          const int h = nn >> 6, d = nn & 63;
          const size_t bhsd = ((size_t)(b * 16 + h) * 2048 + s) * 64 + d;
          if (sec == 0){
            q_bf[bhsd] = f2b(v * 0.1803368801111204f);      // 1/8 * log2(e)
          } else if (sec == 1){
            k_bf[bhsd] = f2b(v);
            Cout[8388608 + bhsd] = v;                       // present[0] = k
          } else {
            vT_bf[((size_t)(b * 16 + h) * 64 + d) * 2048 + s] = f2b(v);
            Cout[16777216 + bhsd] = v;                      // present[1] = v
          }
        }
      }
    }
  }
}

// ---------------- causal flash attention ----------------
// grid (8,64) = 512 blocks, 4 waves. Block = 128-row q-tile pair {15-bx, bx}
// (uniform 34 staging iters). Wave w owns rows w*32..w*32+31 (2 x 16-row
// groups). K/V staged ONCE per block per KV-step into double-buffered LDS
// via global_load_lds (16KB/iter, 4x less L1 traffic than per-wave loads).
// LDS tiles XOR-swizzled: global source chunk pre-swizzled (linear LDS dest),
// ds_read applies the same involution -> conflict-free b128 reads.
// Swapped QK^T (mfma(K,Q)): lane holds 16 scores of one q-row -> softmax =
// in-lane tree + 2 shfl_xor; defer-max THR=8; hw v_exp_f32. XCD remap keeps
// each head's 8 blocks on one XCD (K/V L2-resident).
__global__ __launch_bounds__(256) void attn_kern(
    const u16* __restrict__ q_bf, const u16* __restrict__ k_bf,
    const u16* __restrict__ vT_bf, u16* __restrict__ a_bf)
{
  const int S = 2048;
  // ---- XCD-locality block remap (bijective on [0,512)) ----
  const int id = (int)blockIdx.x + 8 * (int)blockIdx.y;
  const int xcd = id & 7, j = id >> 3;
  const int bh = xcd + 8 * (j & 7);   // all 8 blocks of a head share id%8
  const int bx = j >> 3;              // 0..7

  const int tid = threadIdx.x, w = tid >> 6, lane = tid & 63;
  const int l15 = lane & 15, lhi = lane >> 4;
  const u16* qp = q_bf + (size_t)bh * S * 64;
  const char* kbytes = (const char*)(k_bf + (size_t)bh * S * 64);
  const char* vbytes = (const char*)(vT_bf + (size_t)bh * 64 * S);
  const int b = bh >> 4, h = bh & 15;

  __shared__ u16 Kbuf[2][64 * 64];
  __shared__ u16 Vbuf[2][64 * 64];
  __shared__ u16 P_all[4][32 * 64];
  char* Pc = (char*)&P_all[w][0];
  const int swz = (l15 & 7) << 4;

  // staging geometry: 512 x 16B chunks per 8KB tile, 2 per thread.
  // rows srow and srow+32 share the same chunk swizzle ((row&7) invariant).
  const int srow = tid >> 3;                 // 0..31
  const int sch  = (tid & 7) ^ (srow & 7);   // pre-swizzled source chunk

  // per-group softmax + P-pack + PV
  auto process = [&](f32x4 (&s)[4], float &m, float &l, f32x4 (&o)[4],
                     const bf16x8 (&vf)[8], int qr0g, bool domask, int jb, int gofs){
    if (domask){
      const int q = qr0g + l15;
#pragma unroll
      for (int nf = 0; nf < 4; ++nf)
#pragma unroll
        for (int r = 0; r < 4; ++r){
          const int kv = jb + nf * 16 + lhi * 4 + r;
          if (kv > q) s[nf][r] = -1e10f;
        }
    }
    float a0 = fmaxf(s[0][0], s[0][1]), a1 = fmaxf(s[0][2], s[0][3]);
    float a2 = fmaxf(s[1][0], s[1][1]), a3 = fmaxf(s[1][2], s[1][3]);
    float a4 = fmaxf(s[2][0], s[2][1]), a5 = fmaxf(s[2][2], s[2][3]);
    float a6 = fmaxf(s[3][0], s[3][1]), a7 = fmaxf(s[3][2], s[3][3]);
    float x = fmaxf(fmaxf(fmaxf(a0,a1), fmaxf(a2,a3)),
                    fmaxf(fmaxf(a4,a5), fmaxf(a6,a7)));
    x = fmaxf(x, __shfl_xor(x, 16));
    x = fmaxf(x, __shfl_xor(x, 32));
    if (__any(x - m > 8.0f)){
      const float mn = fmaxf(m, x);
      const float sc = fexp2(m - mn);
      m = mn;
      l *= sc;
      float scq[4];
#pragma unroll
      for (int r = 0; r < 4; ++r)
        scq[r] = __shfl(sc, (lane & 48) | (lhi * 4 + r));
#pragma unroll
      for (int df = 0; df < 4; ++df)
#pragma unroll
        for (int r = 0; r < 4; ++r) o[df][r] *= scq[r];
    }
    float p[16];
#pragma unroll
    for (int nf = 0; nf < 4; ++nf)
#pragma unroll
      for (int r = 0; r < 4; ++r) p[nf*4+r] = fexp2(s[nf][r] - m);
    float rs = (((p[0]+p[1])+(p[2]+p[3])) + ((p[4]+p[5])+(p[6]+p[7])))
             + (((p[8]+p[9])+(p[10]+p[11])) + ((p[12]+p[13])+(p[14]+p[15])));
    rs += __shfl_xor(rs, 16);
    rs += __shfl_xor(rs, 32);
    l += rs;
#pragma unroll
    for (int nf = 0; nf < 4; ++nf){
      bf16x4v pk;
#pragma unroll
      for (int r = 0; r < 4; ++r) pk[r] = (__bf16)p[nf*4+r];
      *(bf16x4v*)(Pc + gofs + ((l15 * 128 + nf * 32 + lhi * 8) ^ swz)) = pk;
    }
    __builtin_amdgcn_s_setprio(1);
#pragma unroll
    for (int kk = 0; kk < 2; ++kk){
      const bf16x8 pa = *(const bf16x8*)(Pc + gofs + ((l15 * 128 + kk * 64 + lhi * 16) ^ swz));
#pragma unroll
      for (int df = 0; df < 4; ++df)
        o[df] = MFMA16(pa, vf[kk*4+df], o[df]);
    }
    __builtin_amdgcn_s_setprio(0);
  };

  for (int half = 0; half < 2; ++half){
    const int qt = (half == 0) ? (15 - bx) : bx;     // 128-row q-tile index
    const int qr0 = qt * 128 + w * 32;

    bf16x8 qf[2][2];
#pragma unroll
    for (int g = 0; g < 2; ++g){
      qf[g][0] = *(const bf16x8*)&qp[(qr0 + g * 16 + l15) * 64 + lhi * 8];
      qf[g][1] = *(const bf16x8*)&qp[(qr0 + g * 16 + l15) * 64 + 32 + lhi * 8];
    }

    f32x4 o[2][4];
#pragma unroll
    for (int g = 0; g < 2; ++g)
#pragma unroll
      for (int df = 0; df < 4; ++df) o[g][df] = f32x4{0.f,0.f,0.f,0.f};
    float m[2] = {-1e30f, -1e30f}, l[2] = {0.f, 0.f};

    const int nStage = 2 * qt + 2;            // KV tiles staged by the block
    const int nC = 2 * qt + 1 + (w >> 1);     // KV tiles this wave computes
    int cur = 0;

    // prologue: stage KV tile 0 into buffer 0
    gload_lds16(kbytes + (size_t)srow * 128 + sch * 16,        (char*)Kbuf[0] + w * 1024);
    gload_lds16(kbytes + (size_t)(srow + 32) * 128 + sch * 16, (char*)Kbuf[0] + 4096 + w * 1024);
    gload_lds16(vbytes + (size_t)srow * 4096 + sch * 16,        (char*)Vbuf[0] + w * 1024);
    gload_lds16(vbytes + (size_t)(srow + 32) * 4096 + sch * 16, (char*)Vbuf[0] + 4096 + w * 1024);
    __syncthreads();

    for (int it = 0; it < nStage; ++it){
      const int jb = it * 64;
      // issue next-tile staging into the other buffer (no wait)
      if (it + 1 < nStage){
        const char* kb2 = kbytes + (size_t)(jb + 64) * 128;
        const char* vb2 = vbytes + (size_t)(jb + 64) * 2;
        char* kd = (char*)Kbuf[cur ^ 1];
        char* vd = (char*)Vbuf[cur ^ 1];
        gload_lds16(kb2 + (size_t)srow * 128 + sch * 16,        kd + w * 1024);
        gload_lds16(kb2 + (size_t)(srow + 32) * 128 + sch * 16, kd + 4096 + w * 1024);
        gload_lds16(vb2 + (size_t)srow * 4096 + sch * 16,        vd + w * 1024);
        gload_lds16(vb2 + (size_t)(srow + 32) * 4096 + sch * 16, vd + 4096 + w * 1024);
      }
      if (it < nC){
        const char* Kc = (const char*)Kbuf[cur];
        const char* Vc = (const char*)Vbuf[cur];
        // K fragments from LDS (swizzled; row&7 == l15&7)
        bf16x8 kf[8];
#pragma unroll
        for (int nf = 0; nf < 4; ++nf)
#pragma unroll
          for (int kk = 0; kk < 2; ++kk)
            kf[2*nf+kk] = *(const bf16x8*)(Kc + (((nf * 16 + l15) * 128 + kk * 64 + lhi * 16) ^ swz));
        // QK^T swapped: q-col = l15, kv = nf*16 + lhi*4 + r
        f32x4 s[2][4];
        __builtin_amdgcn_s_setprio(1);
#pragma unroll
        for (int g = 0; g < 2; ++g)
#pragma unroll
          for (int nf = 0; nf < 4; ++nf){
            f32x4 z = {0.f, 0.f, 0.f, 0.f};
            z = MFMA16(kf[2*nf], qf[g][0], z);
            z = MFMA16(kf[2*nf+1], qf[g][1], z);
            s[g][nf] = z;
          }
        __builtin_amdgcn_s_setprio(0);
        // V fragments from LDS
        bf16x8 vf[8];
#pragma unroll
        for (int kk = 0; kk < 2; ++kk)
#pragma unroll
          for (int df = 0; df < 4; ++df)
            vf[kk*4+df] = *(const bf16x8*)(Vc + (((df * 16 + l15) * 128 + kk * 64 + lhi * 16) ^ swz));
        const bool domask = (it == nC - 1);
        process(s[0], m[0], l[0], o[0], vf, qr0,      domask, jb, 0);
        process(s[1], m[1], l[1], o[1], vf, qr0 + 16, domask, jb, 2048);
      }
      __syncthreads();   // drains staging (vmcnt) + protects buffer swap
      cur ^= 1;
    }

    // finalize both groups: broadcast 1/l per q-row, store a[b][s][h*64+d]
#pragma unroll
    for (int g = 0; g < 2; ++g){
      const float linv = 1.0f / l[g];
      float lr[4];
#pragma unroll
      for (int r = 0; r < 4; ++r)
        lr[r] = __shfl(linv, (lane & 48) | (lhi * 4 + r));
#pragma unroll
      for (int r = 0; r < 4; ++r){
        const int qrow = qr0 + g * 16 + lhi * 4 + r;
#pragma unroll
        for (int df = 0; df < 4; ++df)
          a_bf[((size_t)b * 2048 + qrow) * 1024 + h * 64 + df * 16 + l15] = f2b(o[g][df][r] * lr[r]);
      }
    }
  }
}

extern "C" void kernel_launch(void* const* d_in, const int* in_sizes, int n_in,
                              void* d_out, int out_size, void* d_ws, size_t ws_size,
                              hipStream_t stream)
{
  const float* x      = (const float*)d_in[0];
  const float* w_attn = (const float*)d_in[1];
  const float* b_attn = (const float*)d_in[2];
  const float* w_proj = (const float*)d_in[3];
  const float* b_proj = (const float*)d_in[4];
  float* out = (float*)d_out;
  char* ws = (char*)d_ws;
  const size_t MB = 1u << 20;
  u16* x_bf  = (u16*)(ws + 0);        // 16 MB, reused as a_bf after attention
  u16* wA_T  = (u16*)(ws + 16 * MB);  // 6 MB
  u16* wP_T  = (u16*)(ws + 22 * MB);  // 2 MB
  u16* q_bf  = (u16*)(ws + 24 * MB);  // 16 MB
  u16* k_bf  = (u16*)(ws + 40 * MB);  // 16 MB
  u16* vT_bf = (u16*)(ws + 56 * MB);  // 16 MB
  u16* a_bf  = x_bf;

  cvt_bf16<<<dim3(8192), dim3(256), 0, stream>>>(x, x_bf, 4 * 2048 * 1024);
  transpose_cvt<<<dim3(96, 32), dim3(32, 8), 0, stream>>>(w_attn, wA_T, 1024, 3072);
  transpose_cvt<<<dim3(32, 32), dim3(32, 8), 0, stream>>>(w_proj, wP_T, 1024, 1024);
  gemm_bf16<1><<<dim3(24, 64), dim3(256), 0, stream>>>(
      x_bf, wA_T, b_attn, out, q_bf, k_bf, vT_bf, 8192, 3072, 1024);
  attn_kern<<<dim3(8, 64), dim3(256), 0, stream>>>(q_bf, k_bf, vT_bf, a_bf);
  gemm_bf16<0><<<dim3(8, 64), dim3(256), 0, stream>>>(
      a_bf, wP_T, b_proj, out, nullptr, nullptr, nullptr, 8192, 1024, 1024);
}

// Round 9
// 209.677 us; speedup vs baseline: 1.5830x; 1.0720x over previous
//
#include <hip/hip_runtime.h>
#include <stdint.h>

typedef unsigned short u16;
typedef __attribute__((ext_vector_type(8))) __bf16 bf16x8;
typedef __attribute__((ext_vector_type(4))) __bf16 bf16x4v;
typedef __attribute__((ext_vector_type(4))) float f32x4;
typedef __attribute__((ext_vector_type(4))) unsigned short u16x4;
typedef __attribute__((ext_vector_type(8))) unsigned short u16x8;

#define MFMA16(a,b,c) __builtin_amdgcn_mfma_f32_16x16x32_bf16(a,b,c,0,0,0)

// hardware v_exp_f32 (2^x)
static __device__ __forceinline__ float fexp2(float x){
#if __has_builtin(__builtin_amdgcn_exp2f)
  return __builtin_amdgcn_exp2f(x);
#else
  float r; asm("v_exp_f32 %0, %1" : "=v"(r) : "v"(x)); return r;
#endif
}

// f32 -> bf16 bits, round-to-nearest-even
static __device__ __forceinline__ u16 f2b(float f){
  uint32_t u = __float_as_uint(f);
  u += 0x7fffu + ((u >> 16) & 1u);
  return (u16)(u >> 16);
}

static __device__ __forceinline__ void gload_lds16(const void* g, void* l){
  __builtin_amdgcn_global_load_lds(
      (__attribute__((address_space(1))) void*)(uintptr_t)g,
      (__attribute__((address_space(3))) void*)(uintptr_t)l,
      16, 0, 0);
}

// ---------------- fp32 -> bf16 elementwise ----------------
__global__ __launch_bounds__(256) void cvt_bf16(const float* __restrict__ in,
                                                u16* __restrict__ out, int n){
  int i = (blockIdx.x * 256 + threadIdx.x) * 4;
  if (i >= n) return;
  float4 v = *(const float4*)(in + i);
  u16x4 o;
  o.x = f2b(v.x); o.y = f2b(v.y); o.z = f2b(v.z); o.w = f2b(v.w);
  *(u16x4*)(out + i) = o;
}

// ---------------- transpose+convert: in[K][N] f32 -> out[N][K] bf16 ----------------
__global__ __launch_bounds__(256) void transpose_cvt(const float* __restrict__ in,
                                                     u16* __restrict__ out,
                                                     int K, int N){
  __shared__ float tile[32][33];
  const int nb = blockIdx.x * 32, kb = blockIdx.y * 32;
  const int tx = threadIdx.x, ty = threadIdx.y; // (32,8)
#pragma unroll
  for (int i = 0; i < 32; i += 8)
    tile[ty + i][tx] = in[(size_t)(kb + ty + i) * N + nb + tx];
  __syncthreads();
#pragma unroll
  for (int i = 0; i < 32; i += 8)
    out[(size_t)(nb + ty + i) * K + kb + tx] = f2b(tile[tx][ty + i]);
}

// ---------------- bf16 GEMM: C[M,N] = A[M,K] * Bt[N,K]^T + bias ----------------
// MODE 0: write fp32 C to Cout[M,N].
// MODE 1 (QKV): q/k through LDS-retile -> coalesced b128 bf16 stores;
//               v packed along s (acc r-index) -> b64 stores; present fp32 direct.
template<int MODE>
__global__ __launch_bounds__(256) void gemm_bf16(
    const u16* __restrict__ A, const u16* __restrict__ Bt,
    const float* __restrict__ bias, float* __restrict__ Cout,
    u16* __restrict__ q_bf, u16* __restrict__ k_bf, u16* __restrict__ vT_bf,
    int M, int N, int K)
{
  __shared__ u16 smem[16384];          // As | Bs during loop; T (128x128 bf16) in epilogue
  u16* As = smem;
  u16* Bs = smem + 8192;
  const int tid = threadIdx.x;
  const int w = tid >> 6, lane = tid & 63;
  const int l15 = lane & 15, lhi = lane >> 4;
  const int mBase = blockIdx.y * 128, nBase = blockIdx.x * 128;
  const int wr = w >> 1, wc = w & 1;

  f32x4 acc[4][4];
#pragma unroll
  for (int i = 0; i < 4; ++i)
#pragma unroll
    for (int j = 0; j < 4; ++j) acc[i][j] = f32x4{0.f, 0.f, 0.f, 0.f};

  const int nK = K >> 6;
  for (int kt = 0; kt < nK; ++kt){
    const int kb = kt << 6;
#pragma unroll
    for (int i = 0; i < 4; ++i){
      const int idx = i * 256 + tid;
      const int row = idx >> 3, c8 = idx & 7;
      gload_lds16(A  + (size_t)(mBase + row) * K + kb + c8 * 8,
                  As + (size_t)(i * 256 + w * 64) * 8);
      gload_lds16(Bt + (size_t)(nBase + row) * K + kb + c8 * 8,
                  Bs + (size_t)(i * 256 + w * 64) * 8);
    }
    __syncthreads();
#pragma unroll
    for (int kk = 0; kk < 2; ++kk){
      bf16x8 af[4], bb[4];
#pragma unroll
      for (int mi = 0; mi < 4; ++mi)
        af[mi] = *(const bf16x8*)&As[(wr * 64 + mi * 16 + l15) * 64 + kk * 32 + lhi * 8];
#pragma unroll
      for (int ni = 0; ni < 4; ++ni)
        bb[ni] = *(const bf16x8*)&Bs[(wc * 64 + ni * 16 + l15) * 64 + kk * 32 + lhi * 8];
#pragma unroll
      for (int mi = 0; mi < 4; ++mi)
#pragma unroll
        for (int ni = 0; ni < 4; ++ni)
          acc[mi][ni] = MFMA16(af[mi], bb[ni], acc[mi][ni]);
    }
    __syncthreads();
  }

  // ---------------- epilogue ----------------
  if (MODE == 0){
#pragma unroll
    for (int ni = 0; ni < 4; ++ni){
      const int col = nBase + wc * 64 + ni * 16 + l15;
      const float bv = bias[col];
#pragma unroll
      for (int mi = 0; mi < 4; ++mi)
#pragma unroll
        for (int r = 0; r < 4; ++r){
          const int row = mBase + wr * 64 + mi * 16 + lhi * 4 + r;
          Cout[(size_t)row * N + col] = acc[mi][ni][r] + bv;
        }
    }
    return;
  }

  // MODE 1: each block lies in one section (N tiles of 128 inside 1024-col sections)
  const int sec = nBase >> 10;          // 0=q, 1=k, 2=v
  const int nn0 = nBase & 1023;
  const int bb  = mBase >> 11;          // batch
  const int s0  = mBase & 2047;         // seq base

  if (sec == 2){
    // v: vT_bf[(bh*64+d)*2048+s] packed along r (s-contiguous) + present1 fp32
#pragma unroll
    for (int ni = 0; ni < 4; ++ni){
      const int c = wc * 64 + ni * 16 + l15;
      const int nn = nn0 + c;
      const int h = nn >> 6, d = nn & 63;
      const float bv = bias[nBase + c];
#pragma unroll
      for (int mi = 0; mi < 4; ++mi){
        const int sb = s0 + wr * 64 + mi * 16 + lhi * 4;
        u16x4 pk;
#pragma unroll
        for (int r = 0; r < 4; ++r){
          const float v = acc[mi][ni][r] + bv;
          pk[r] = f2b(v);
          Cout[16777216 + ((size_t)(bb * 16 + h) * 2048 + sb + r) * 64 + d] = v;
        }
        *(u16x4*)(vT_bf + ((size_t)(bb * 16 + h) * 64 + d) * 2048 + sb) = pk;
      }
    }
    return;
  }

  // q or k: stage bf16 tile into LDS (16B-granular XOR swizzle), then b128 stores
  const float qscl = (sec == 0) ? 0.1803368801111204f : 1.0f;   // 1/8*log2e for q
#pragma unroll
  for (int ni = 0; ni < 4; ++ni){
    const int c = wc * 64 + ni * 16 + l15;
    const float bv = bias[nBase + c];
#pragma unroll
    for (int mi = 0; mi < 4; ++mi)
#pragma unroll
      for (int r = 0; r < 4; ++r){
        const int rl = wr * 64 + mi * 16 + lhi * 4 + r;
        const float v = (acc[mi][ni][r] + bv) * qscl;
        smem[rl * 128 + (c ^ ((rl & 7) << 3))] = f2b(v);
      }
  }
  if (sec == 1){
    // present0 fp32 direct from registers (full 64B lines per 16-lane group)
#pragma unroll
    for (int ni = 0; ni < 4; ++ni){
      const int c = wc * 64 + ni * 16 + l15;
      const int nn = nn0 + c;
      const int h = nn >> 6, d = nn & 63;
      const float bv = bias[nBase + c];
#pragma unroll
      for (int mi = 0; mi < 4; ++mi)
#pragma unroll
        for (int r = 0; r < 4; ++r){
          const int s = s0 + wr * 64 + mi * 16 + lhi * 4 + r;
          Cout[8388608 + ((size_t)(bb * 16 + h) * 2048 + s) * 64 + d] = acc[mi][ni][r] + bv;
        }
    }
  }
  __syncthreads();
  {
    const int rl = tid >> 1, hh = tid & 1;
    const int h = (nn0 >> 6) + hh;
    u16* dst = (sec == 0 ? q_bf : k_bf) + ((size_t)(bb * 16 + h) * 2048 + s0 + rl) * 64;
#pragma unroll
    for (int i = 0; i < 8; ++i){
      const int c0 = hh * 64 + i * 8;
      u16x8 vv = *(const u16x8*)&smem[rl * 128 + (c0 ^ ((rl & 7) << 3))];
      *(u16x8*)(dst + i * 8) = vv;
    }
  }
}

// ---------------- causal flash attention ----------------
// (unchanged from round 8 — 512 blocks, LDS-staged double-buffered K/V,
//  swapped QK^T, defer-max, hw exp2, XCD remap)
__global__ __launch_bounds__(256) void attn_kern(
    const u16* __restrict__ q_bf, const u16* __restrict__ k_bf,
    const u16* __restrict__ vT_bf, u16* __restrict__ a_bf)
{
  const int S = 2048;
  const int id = (int)blockIdx.x + 8 * (int)blockIdx.y;
  const int xcd = id & 7, j = id >> 3;
  const int bh = xcd + 8 * (j & 7);
  const int bx = j >> 3;

  const int tid = threadIdx.x, w = tid >> 6, lane = tid & 63;
  const int l15 = lane & 15, lhi = lane >> 4;
  const u16* qp = q_bf + (size_t)bh * S * 64;
  const char* kbytes = (const char*)(k_bf + (size_t)bh * S * 64);
  const char* vbytes = (const char*)(vT_bf + (size_t)bh * 64 * S);
  const int b = bh >> 4, h = bh & 15;

  __shared__ u16 Kbuf[2][64 * 64];
  __shared__ u16 Vbuf[2][64 * 64];
  __shared__ u16 P_all[4][32 * 64];
  char* Pc = (char*)&P_all[w][0];
  const int swz = (l15 & 7) << 4;

  const int srow = tid >> 3;
  const int sch  = (tid & 7) ^ (srow & 7);

  auto process = [&](f32x4 (&s)[4], float &m, float &l, f32x4 (&o)[4],
                     const bf16x8 (&vf)[8], int qr0g, bool domask, int jb, int gofs){
    if (domask){
      const int q = qr0g + l15;
#pragma unroll
      for (int nf = 0; nf < 4; ++nf)
#pragma unroll
        for (int r = 0; r < 4; ++r){
          const int kv = jb + nf * 16 + lhi * 4 + r;
          if (kv > q) s[nf][r] = -1e10f;
        }
    }
    float a0 = fmaxf(s[0][0], s[0][1]), a1 = fmaxf(s[0][2], s[0][3]);
    float a2 = fmaxf(s[1][0], s[1][1]), a3 = fmaxf(s[1][2], s[1][3]);
    float a4 = fmaxf(s[2][0], s[2][1]), a5 = fmaxf(s[2][2], s[2][3]);
    float a6 = fmaxf(s[3][0], s[3][1]), a7 = fmaxf(s[3][2], s[3][3]);
    float x = fmaxf(fmaxf(fmaxf(a0,a1), fmaxf(a2,a3)),
                    fmaxf(fmaxf(a4,a5), fmaxf(a6,a7)));
    x = fmaxf(x, __shfl_xor(x, 16));
    x = fmaxf(x, __shfl_xor(x, 32));
    if (__any(x - m > 8.0f)){
      const float mn = fmaxf(m, x);
      const float sc = fexp2(m - mn);
      m = mn;
      l *= sc;
      float scq[4];
#pragma unroll
      for (int r = 0; r < 4; ++r)
        scq[r] = __shfl(sc, (lane & 48) | (lhi * 4 + r));
#pragma unroll
      for (int df = 0; df < 4; ++df)
#pragma unroll
        for (int r = 0; r < 4; ++r) o[df][r] *= scq[r];
    }
    float p[16];
#pragma unroll
    for (int nf = 0; nf < 4; ++nf)
#pragma unroll
      for (int r = 0; r < 4; ++r) p[nf*4+r] = fexp2(s[nf][r] - m);
    float rs = (((p[0]+p[1])+(p[2]+p[3])) + ((p[4]+p[5])+(p[6]+p[7])))
             + (((p[8]+p[9])+(p[10]+p[11])) + ((p[12]+p[13])+(p[14]+p[15])));
    rs += __shfl_xor(rs, 16);
    rs += __shfl_xor(rs, 32);
    l += rs;
#pragma unroll
    for (int nf = 0; nf < 4; ++nf){
      bf16x4v pk;
#pragma unroll
      for (int r = 0; r < 4; ++r) pk[r] = (__bf16)p[nf*4+r];
      *(bf16x4v*)(Pc + gofs + ((l15 * 128 + nf * 32 + lhi * 8) ^ swz)) = pk;
    }
    __builtin_amdgcn_s_setprio(1);
#pragma unroll
    for (int kk = 0; kk < 2; ++kk){
      const bf16x8 pa = *(const bf16x8*)(Pc + gofs + ((l15 * 128 + kk * 64 + lhi * 16) ^ swz));
#pragma unroll
      for (int df = 0; df < 4; ++df)
        o[df] = MFMA16(pa, vf[kk*4+df], o[df]);
    }
    __builtin_amdgcn_s_setprio(0);
  };

  for (int half = 0; half < 2; ++half){
    const int qt = (half == 0) ? (15 - bx) : bx;
    const int qr0 = qt * 128 + w * 32;

    bf16x8 qf[2][2];
#pragma unroll
    for (int g = 0; g < 2; ++g){
      qf[g][0] = *(const bf16x8*)&qp[(qr0 + g * 16 + l15) * 64 + lhi * 8];
      qf[g][1] = *(const bf16x8*)&qp[(qr0 + g * 16 + l15) * 64 + 32 + lhi * 8];
    }

    f32x4 o[2][4];
#pragma unroll
    for (int g = 0; g < 2; ++g)
#pragma unroll
      for (int df = 0; df < 4; ++df) o[g][df] = f32x4{0.f,0.f,0.f,0.f};
    float m[2] = {-1e30f, -1e30f}, l[2] = {0.f, 0.f};

    const int nStage = 2 * qt + 2;
    const int nC = 2 * qt + 1 + (w >> 1);
    int cur = 0;

    gload_lds16(kbytes + (size_t)srow * 128 + sch * 16,        (char*)Kbuf[0] + w * 1024);
    gload_lds16(kbytes + (size_t)(srow + 32) * 128 + sch * 16, (char*)Kbuf[0] + 4096 + w * 1024);
    gload_lds16(vbytes + (size_t)srow * 4096 + sch * 16,        (char*)Vbuf[0] + w * 1024);
    gload_lds16(vbytes + (size_t)(srow + 32) * 4096 + sch * 16, (char*)Vbuf[0] + 4096 + w * 1024);
    __syncthreads();

    for (int it = 0; it < nStage; ++it){
      const int jb = it * 64;
      if (it + 1 < nStage){
        const char* kb2 = kbytes + (size_t)(jb + 64) * 128;
        const char* vb2 = vbytes + (size_t)(jb + 64) * 2;
        char* kd = (char*)Kbuf[cur ^ 1];
        char* vd = (char*)Vbuf[cur ^ 1];
        gload_lds16(kb2 + (size_t)srow * 128 + sch * 16,        kd + w * 1024);
        gload_lds16(kb2 + (size_t)(srow + 32) * 128 + sch * 16, kd + 4096 + w * 1024);
        gload_lds16(vb2 + (size_t)srow * 4096 + sch * 16,        vd + w * 1024);
        gload_lds16(vb2 + (size_t)(srow + 32) * 4096 + sch * 16, vd + 4096 + w * 1024);
      }
      if (it < nC){
        const char* Kc = (const char*)Kbuf[cur];
        const char* Vc = (const char*)Vbuf[cur];
        bf16x8 kf[8];
#pragma unroll
        for (int nf = 0; nf < 4; ++nf)
#pragma unroll
          for (int kk = 0; kk < 2; ++kk)
            kf[2*nf+kk] = *(const bf16x8*)(Kc + (((nf * 16 + l15) * 128 + kk * 64 + lhi * 16) ^ swz));
        f32x4 s[2][4];
        __builtin_amdgcn_s_setprio(1);
#pragma unroll
        for (int g = 0; g < 2; ++g)
#pragma unroll
          for (int nf = 0; nf < 4; ++nf){
            f32x4 z = {0.f, 0.f, 0.f, 0.f};
            z = MFMA16(kf[2*nf], qf[g][0], z);
            z = MFMA16(kf[2*nf+1], qf[g][1], z);
            s[g][nf] = z;
          }
        __builtin_amdgcn_s_setprio(0);
        bf16x8 vf[8];
#pragma unroll
        for (int kk = 0; kk < 2; ++kk)
#pragma unroll
          for (int df = 0; df < 4; ++df)
            vf[kk*4+df] = *(const bf16x8*)(Vc + (((df * 16 + l15) * 128 + kk * 64 + lhi * 16) ^ swz));
        const bool domask = (it == nC - 1);
        process(s[0], m[0], l[0], o[0], vf, qr0,      domask, jb, 0);
        process(s[1], m[1], l[1], o[1], vf, qr0 + 16, domask, jb, 2048);
      }
      __syncthreads();
      cur ^= 1;
    }

#pragma unroll
    for (int g = 0; g < 2; ++g){
      const float linv = 1.0f / l[g];
      float lr[4];
#pragma unroll
      for (int r = 0; r < 4; ++r)
        lr[r] = __shfl(linv, (lane & 48) | (lhi * 4 + r));
#pragma unroll
      for (int r = 0; r < 4; ++r){
        const int qrow = qr0 + g * 16 + lhi * 4 + r;
#pragma unroll
        for (int df = 0; df < 4; ++df)
          a_bf[((size_t)b * 2048 + qrow) * 1024 + h * 64 + df * 16 + l15] = f2b(o[g][df][r] * lr[r]);
      }
    }
  }
}

extern "C" void kernel_launch(void* const* d_in, const int* in_sizes, int n_in,
                              void* d_out, int out_size, void* d_ws, size_t ws_size,
                              hipStream_t stream)
{
  const float* x      = (const float*)d_in[0];
  const float* w_attn = (const float*)d_in[1];
  const float* b_attn = (const float*)d_in[2];
  const float* w_proj = (const float*)d_in[3];
  const float* b_proj = (const float*)d_in[4];
  float* out = (float*)d_out;
  char* ws = (char*)d_ws;
  const size_t MB = 1u << 20;
  u16* x_bf  = (u16*)(ws + 0);        // 16 MB, reused as a_bf after attention
  u16* wA_T  = (u16*)(ws + 16 * MB);  // 6 MB
  u16* wP_T  = (u16*)(ws + 22 * MB);  // 2 MB
  u16* q_bf  = (u16*)(ws + 24 * MB);  // 16 MB
  u16* k_bf  = (u16*)(ws + 40 * MB);  // 16 MB
  u16* vT_bf = (u16*)(ws + 56 * MB);  // 16 MB
  u16* a_bf  = x_bf;

  cvt_bf16<<<dim3(8192), dim3(256), 0, stream>>>(x, x_bf, 4 * 2048 * 1024);
  transpose_cvt<<<dim3(96, 32), dim3(32, 8), 0, stream>>>(w_attn, wA_T, 1024, 3072);
  transpose_cvt<<<dim3(32, 32), dim3(32, 8), 0, stream>>>(w_proj, wP_T, 1024, 1024);
  gemm_bf16<1><<<dim3(24, 64), dim3(256), 0, stream>>>(
      x_bf, wA_T, b_attn, out, q_bf, k_bf, vT_bf, 8192, 3072, 1024);
  attn_kern<<<dim3(8, 64), dim3(256), 0, stream>>>(q_bf, k_bf, vT_bf, a_bf);
  gemm_bf16<0><<<dim3(8, 64), dim3(256), 0, stream>>>(
      a_bf, wP_T, b_proj, out, nullptr, nullptr, nullptr, 8192, 1024, 1024);
}

// Round 10
// 197.955 us; speedup vs baseline: 1.6768x; 1.0592x over previous
//
#include <hip/hip_runtime.h>
#include <stdint.h>

typedef unsigned short u16;
typedef __attribute__((ext_vector_type(8))) __bf16 bf16x8;
typedef __attribute__((ext_vector_type(4))) __bf16 bf16x4v;
typedef __attribute__((ext_vector_type(4))) float f32x4;
typedef __attribute__((ext_vector_type(4))) unsigned short u16x4;
typedef __attribute__((ext_vector_type(8))) unsigned short u16x8;

#define MFMA16(a,b,c) __builtin_amdgcn_mfma_f32_16x16x32_bf16(a,b,c,0,0,0)

// hardware v_exp_f32 (2^x)
static __device__ __forceinline__ float fexp2(float x){
#if __has_builtin(__builtin_amdgcn_exp2f)
  return __builtin_amdgcn_exp2f(x);
#else
  float r; asm("v_exp_f32 %0, %1" : "=v"(r) : "v"(x)); return r;
#endif
}

// f32 -> bf16 bits, round-to-nearest-even
static __device__ __forceinline__ u16 f2b(float f){
  uint32_t u = __float_as_uint(f);
  u += 0x7fffu + ((u >> 16) & 1u);
  return (u16)(u >> 16);
}

static __device__ __forceinline__ void gload_lds16(const void* g, void* l){
  __builtin_amdgcn_global_load_lds(
      (__attribute__((address_space(1))) void*)(uintptr_t)g,
      (__attribute__((address_space(3))) void*)(uintptr_t)l,
      16, 0, 0);
}

// ---------------- fp32 -> bf16 elementwise ----------------
__global__ __launch_bounds__(256) void cvt_bf16(const float* __restrict__ in,
                                                u16* __restrict__ out, int n){
  int i = (blockIdx.x * 256 + threadIdx.x) * 4;
  if (i >= n) return;
  float4 v = *(const float4*)(in + i);
  u16x4 o;
  o.x = f2b(v.x); o.y = f2b(v.y); o.z = f2b(v.z); o.w = f2b(v.w);
  *(u16x4*)(out + i) = o;
}

// ---------------- transpose+convert: in[K][N] f32 -> out[N][K] bf16 ----------------
__global__ __launch_bounds__(256) void transpose_cvt(const float* __restrict__ in,
                                                     u16* __restrict__ out,
                                                     int K, int N){
  __shared__ float tile[32][33];
  const int nb = blockIdx.x * 32, kb = blockIdx.y * 32;
  const int tx = threadIdx.x, ty = threadIdx.y; // (32,8)
#pragma unroll
  for (int i = 0; i < 32; i += 8)
    tile[ty + i][tx] = in[(size_t)(kb + ty + i) * N + nb + tx];
  __syncthreads();
#pragma unroll
  for (int i = 0; i < 32; i += 8)
    out[(size_t)(nb + ty + i) * K + kb + tx] = f2b(tile[tx][ty + i]);
}

// ---------------- QKV GEMM: 256x256 tile, BK=32, 8 waves, 4-deep LDS ring ----
// Counted-vmcnt pipeline: tile kt staged (4 loads/thread) during iteration
// kt-2; at iter top: vmcnt(4) -> oldest 4 loads (tile kt) complete, then
// s_barrier. Staging targets buf[(kt+2)&3], reads buf[kt&3] (disjoint).
// T2: 16B-chunk XOR swizzle, pre-swizzled global source (linear LDS dest).
// Epilogue: q/k via LDS retile -> b128 stores; v packed along s; present fp32.
__global__ __launch_bounds__(512, 2) void gemm256_qkv(
    const u16* __restrict__ A, const u16* __restrict__ Bt,
    const float* __restrict__ bias, float* __restrict__ Cout,
    u16* __restrict__ q_bf, u16* __restrict__ k_bf, u16* __restrict__ vT_bf)
{
  const int K = 1024;
  const int nT = 32;                 // K / 32
  extern __shared__ u16 smem[];      // 4 bufs x (A 16KB + B 16KB) = 128 KB
  const int tid = threadIdx.x;
  const int w = tid >> 6, lane = tid & 63;
  const int l15 = lane & 15, lhi = lane >> 4;
  const int wr = w >> 2, wc = w & 3;           // 2M x 4N wave grid
  const int mBase = blockIdx.y * 256, nBase = blockIdx.x * 256;

  // staging geometry: 16B chunks; row = tid>>2 (0..127), source chunk pre-swizzled
  const int srow = tid >> 2;
  const int sch  = (tid & 3) ^ (srow & 3);
  const u16* Ag = A  + (size_t)(mBase + srow) * K + sch * 8;
  const u16* Bg = Bt + (size_t)(nBase + srow) * K + sch * 8;

  f32x4 acc[8][4];
#pragma unroll
  for (int i = 0; i < 8; ++i)
#pragma unroll
    for (int j = 0; j < 4; ++j) acc[i][j] = f32x4{0.f, 0.f, 0.f, 0.f};

  auto stageA = [&](int kt){
    char* Ab = (char*)smem + (kt & 3) * 32768;
    const int kb = kt << 5;
    gload_lds16(Ag + kb,           Ab + tid * 16);
    gload_lds16(Ag + 128 * K + kb, Ab + 8192 + tid * 16);
  };
  auto stageB = [&](int kt){
    char* Bb = (char*)smem + (kt & 3) * 32768 + 16384;
    const int kb = kt << 5;
    gload_lds16(Bg + kb,           Bb + tid * 16);
    gload_lds16(Bg + 128 * K + kb, Bb + 8192 + tid * 16);
  };

  stageA(0); stageB(0); stageA(1); stageB(1);

  for (int kt = 0; kt < nT; ++kt){
    if (kt == nT - 1) asm volatile("s_waitcnt vmcnt(0)" ::: "memory");
    else              asm volatile("s_waitcnt vmcnt(4)" ::: "memory");
    __builtin_amdgcn_s_barrier();
    const char* Ab = (const char*)smem + (kt & 3) * 32768;
    const char* Bb = Ab + 16384;

    // fragments: row stride 64B = 4 chunks; lds chunk = lhi ^ (row&3)
    bf16x8 b0, b1, b2, b3, a0, a1, a2, a3;
#define LDT(base, row) (*(const bf16x8*)((base) + ((row) << 6) + (((lhi ^ ((row) & 3))) << 4)))
    {
      const int br = wc * 64 + l15;
      b0 = LDT(Bb, br); b1 = LDT(Bb, br + 16); b2 = LDT(Bb, br + 32); b3 = LDT(Bb, br + 48);
      const int ar = wr * 128 + l15;
      a0 = LDT(Ab, ar); a1 = LDT(Ab, ar + 16); a2 = LDT(Ab, ar + 32); a3 = LDT(Ab, ar + 48);
    }
    if (kt + 2 < nT) stageA(kt + 2);
    __builtin_amdgcn_s_setprio(1);
    acc[0][0] = MFMA16(a0, b0, acc[0][0]); acc[0][1] = MFMA16(a0, b1, acc[0][1]);
    acc[0][2] = MFMA16(a0, b2, acc[0][2]); acc[0][3] = MFMA16(a0, b3, acc[0][3]);
    acc[1][0] = MFMA16(a1, b0, acc[1][0]); acc[1][1] = MFMA16(a1, b1, acc[1][1]);
    acc[1][2] = MFMA16(a1, b2, acc[1][2]); acc[1][3] = MFMA16(a1, b3, acc[1][3]);
    acc[2][0] = MFMA16(a2, b0, acc[2][0]); acc[2][1] = MFMA16(a2, b1, acc[2][1]);
    acc[2][2] = MFMA16(a2, b2, acc[2][2]); acc[2][3] = MFMA16(a2, b3, acc[2][3]);
    acc[3][0] = MFMA16(a3, b0, acc[3][0]); acc[3][1] = MFMA16(a3, b1, acc[3][1]);
    acc[3][2] = MFMA16(a3, b2, acc[3][2]); acc[3][3] = MFMA16(a3, b3, acc[3][3]);
    __builtin_amdgcn_s_setprio(0);
    {
      const int ar = wr * 128 + 64 + l15;
      a0 = LDT(Ab, ar); a1 = LDT(Ab, ar + 16); a2 = LDT(Ab, ar + 32); a3 = LDT(Ab, ar + 48);
    }
    if (kt + 2 < nT) stageB(kt + 2);
    __builtin_amdgcn_s_setprio(1);
    acc[4][0] = MFMA16(a0, b0, acc[4][0]); acc[4][1] = MFMA16(a0, b1, acc[4][1]);
    acc[4][2] = MFMA16(a0, b2, acc[4][2]); acc[4][3] = MFMA16(a0, b3, acc[4][3]);
    acc[5][0] = MFMA16(a1, b0, acc[5][0]); acc[5][1] = MFMA16(a1, b1, acc[5][1]);
    acc[5][2] = MFMA16(a1, b2, acc[5][2]); acc[5][3] = MFMA16(a1, b3, acc[5][3]);
    acc[6][0] = MFMA16(a2, b0, acc[6][0]); acc[6][1] = MFMA16(a2, b1, acc[6][1]);
    acc[6][2] = MFMA16(a2, b2, acc[6][2]); acc[6][3] = MFMA16(a2, b3, acc[6][3]);
    acc[7][0] = MFMA16(a3, b0, acc[7][0]); acc[7][1] = MFMA16(a3, b1, acc[7][1]);
    acc[7][2] = MFMA16(a3, b2, acc[7][2]); acc[7][3] = MFMA16(a3, b3, acc[7][3]);
    __builtin_amdgcn_s_setprio(0);
#undef LDT
  }
  __syncthreads();

  // ---------------- epilogue ----------------
  const int sec = nBase >> 10;          // 0=q, 1=k, 2=v (256 | 1024 -> uniform)
  const int nn0 = nBase & 1023;
  const int bb_ = mBase >> 11;
  const int s0  = mBase & 2047;

  if (sec == 2){
#pragma unroll
    for (int ni = 0; ni < 4; ++ni){
      const int c = wc * 64 + ni * 16 + l15;
      const int nn = nn0 + c;
      const int h = nn >> 6, d = nn & 63;
      const float bv = bias[nBase + c];
#pragma unroll
      for (int mi = 0; mi < 8; ++mi){
        const int sb = s0 + wr * 128 + mi * 16 + lhi * 4;
        u16x4 pk;
#pragma unroll
        for (int r = 0; r < 4; ++r){
          const float v = acc[mi][ni][r] + bv;
          pk[r] = f2b(v);
          Cout[16777216 + ((size_t)(bb_ * 16 + h) * 2048 + sb + r) * 64 + d] = v;
        }
        *(u16x4*)(vT_bf + ((size_t)(bb_ * 16 + h) * 64 + d) * 2048 + sb) = pk;
      }
    }
    return;
  }

  // q or k: retile through LDS (256x256 bf16, 8-u16-block XOR swizzle)
  const float qscl = (sec == 0) ? 0.1803368801111204f : 1.0f;
#pragma unroll
  for (int ni = 0; ni < 4; ++ni){
    const int c = wc * 64 + ni * 16 + l15;
    const float bv = bias[nBase + c];
#pragma unroll
    for (int mi = 0; mi < 8; ++mi)
#pragma unroll
      for (int r = 0; r < 4; ++r){
        const int rl = wr * 128 + mi * 16 + lhi * 4 + r;
        smem[rl * 256 + (c ^ ((rl & 7) << 3))] = f2b((acc[mi][ni][r] + bv) * qscl);
      }
  }
  if (sec == 1){
#pragma unroll
    for (int ni = 0; ni < 4; ++ni){
      const int c = wc * 64 + ni * 16 + l15;
      const int nn = nn0 + c;
      const int h = nn >> 6, d = nn & 63;
      const float bv = bias[nBase + c];
#pragma unroll
      for (int mi = 0; mi < 8; ++mi)
#pragma unroll
        for (int r = 0; r < 4; ++r){
          const int s = s0 + wr * 128 + mi * 16 + lhi * 4 + r;
          Cout[8388608 + ((size_t)(bb_ * 16 + h) * 2048 + s) * 64 + d] = acc[mi][ni][r] + bv;
        }
    }
  }
  __syncthreads();
  {
    const int row = tid >> 1, half = tid & 1;
    u16* base = (sec == 0 ? q_bf : k_bf);
#pragma unroll
    for (int i = 0; i < 16; ++i){
      const int c0 = half * 128 + i * 8;
      const int h = (nn0 >> 6) + (c0 >> 6);
      u16x8 vv = *(const u16x8*)&smem[row * 256 + (c0 ^ ((row & 7) << 3))];
      *(u16x8*)(base + ((size_t)(bb_ * 16 + h) * 2048 + s0 + row) * 64 + (c0 & 63)) = vv;
    }
  }
}

// ---------------- proj GEMM (fp32 out), 128x128 m97-structure ----------------
__global__ __launch_bounds__(256) void gemm_proj(
    const u16* __restrict__ A, const u16* __restrict__ Bt,
    const float* __restrict__ bias, float* __restrict__ Cout,
    int M, int N, int K)
{
  __shared__ u16 As[128 * 64];
  __shared__ u16 Bs[128 * 64];
  const int tid = threadIdx.x;
  const int w = tid >> 6, lane = tid & 63;
  const int l15 = lane & 15, lhi = lane >> 4;
  const int mBase = blockIdx.y * 128, nBase = blockIdx.x * 128;
  const int wr = w >> 1, wc = w & 1;

  f32x4 acc[4][4];
#pragma unroll
  for (int i = 0; i < 4; ++i)
#pragma unroll
    for (int j = 0; j < 4; ++j) acc[i][j] = f32x4{0.f, 0.f, 0.f, 0.f};

  const int nK = K >> 6;
  for (int kt = 0; kt < nK; ++kt){
    const int kb = kt << 6;
#pragma unroll
    for (int i = 0; i < 4; ++i){
      const int idx = i * 256 + tid;
      const int row = idx >> 3, c8 = idx & 7;
      gload_lds16(A  + (size_t)(mBase + row) * K + kb + c8 * 8,
                  As + (size_t)(i * 256 + w * 64) * 8);
      gload_lds16(Bt + (size_t)(nBase + row) * K + kb + c8 * 8,
                  Bs + (size_t)(i * 256 + w * 64) * 8);
    }
    __syncthreads();
#pragma unroll
    for (int kk = 0; kk < 2; ++kk){
      bf16x8 af[4], bb[4];
#pragma unroll
      for (int mi = 0; mi < 4; ++mi)
        af[mi] = *(const bf16x8*)&As[(wr * 64 + mi * 16 + l15) * 64 + kk * 32 + lhi * 8];
#pragma unroll
      for (int ni = 0; ni < 4; ++ni)
        bb[ni] = *(const bf16x8*)&Bs[(wc * 64 + ni * 16 + l15) * 64 + kk * 32 + lhi * 8];
#pragma unroll
      for (int mi = 0; mi < 4; ++mi)
#pragma unroll
        for (int ni = 0; ni < 4; ++ni)
          acc[mi][ni] = MFMA16(af[mi], bb[ni], acc[mi][ni]);
    }
    __syncthreads();
  }
#pragma unroll
  for (int ni = 0; ni < 4; ++ni){
    const int col = nBase + wc * 64 + ni * 16 + l15;
    const float bv = bias[col];
#pragma unroll
    for (int mi = 0; mi < 4; ++mi)
#pragma unroll
      for (int r = 0; r < 4; ++r){
        const int row = mBase + wr * 64 + mi * 16 + lhi * 4 + r;
        Cout[(size_t)row * N + col] = acc[mi][ni][r] + bv;
      }
  }
}

// ---------------- causal flash attention (unchanged from round 8) ----------------
__global__ __launch_bounds__(256) void attn_kern(
    const u16* __restrict__ q_bf, const u16* __restrict__ k_bf,
    const u16* __restrict__ vT_bf, u16* __restrict__ a_bf)
{
  const int S = 2048;
  const int id = (int)blockIdx.x + 8 * (int)blockIdx.y;
  const int xcd = id & 7, j = id >> 3;
  const int bh = xcd + 8 * (j & 7);
  const int bx = j >> 3;

  const int tid = threadIdx.x, w = tid >> 6, lane = tid & 63;
  const int l15 = lane & 15, lhi = lane >> 4;
  const u16* qp = q_bf + (size_t)bh * S * 64;
  const char* kbytes = (const char*)(k_bf + (size_t)bh * S * 64);
  const char* vbytes = (const char*)(vT_bf + (size_t)bh * 64 * S);
  const int b = bh >> 4, h = bh & 15;

  __shared__ u16 Kbuf[2][64 * 64];
  __shared__ u16 Vbuf[2][64 * 64];
  __shared__ u16 P_all[4][32 * 64];
  char* Pc = (char*)&P_all[w][0];
  const int swz = (l15 & 7) << 4;

  const int srow = tid >> 3;
  const int sch  = (tid & 7) ^ (srow & 7);

  auto process = [&](f32x4 (&s)[4], float &m, float &l, f32x4 (&o)[4],
                     const bf16x8 (&vf)[8], int qr0g, bool domask, int jb, int gofs){
    if (domask){
      const int q = qr0g + l15;
#pragma unroll
      for (int nf = 0; nf < 4; ++nf)
#pragma unroll
        for (int r = 0; r < 4; ++r){
          const int kv = jb + nf * 16 + lhi * 4 + r;
          if (kv > q) s[nf][r] = -1e10f;
        }
    }
    float a0 = fmaxf(s[0][0], s[0][1]), a1 = fmaxf(s[0][2], s[0][3]);
    float a2 = fmaxf(s[1][0], s[1][1]), a3 = fmaxf(s[1][2], s[1][3]);
    float a4 = fmaxf(s[2][0], s[2][1]), a5 = fmaxf(s[2][2], s[2][3]);
    float a6 = fmaxf(s[3][0], s[3][1]), a7 = fmaxf(s[3][2], s[3][3]);
    float x = fmaxf(fmaxf(fmaxf(a0,a1), fmaxf(a2,a3)),
                    fmaxf(fmaxf(a4,a5), fmaxf(a6,a7)));
    x = fmaxf(x, __shfl_xor(x, 16));
    x = fmaxf(x, __shfl_xor(x, 32));
    if (__any(x - m > 8.0f)){
      const float mn = fmaxf(m, x);
      const float sc = fexp2(m - mn);
      m = mn;
      l *= sc;
      float scq[4];
#pragma unroll
      for (int r = 0; r < 4; ++r)
        scq[r] = __shfl(sc, (lane & 48) | (lhi * 4 + r));
#pragma unroll
      for (int df = 0; df < 4; ++df)
#pragma unroll
        for (int r = 0; r < 4; ++r) o[df][r] *= scq[r];
    }
    float p[16];
#pragma unroll
    for (int nf = 0; nf < 4; ++nf)
#pragma unroll
      for (int r = 0; r < 4; ++r) p[nf*4+r] = fexp2(s[nf][r] - m);
    float rs = (((p[0]+p[1])+(p[2]+p[3])) + ((p[4]+p[5])+(p[6]+p[7])))
             + (((p[8]+p[9])+(p[10]+p[11])) + ((p[12]+p[13])+(p[14]+p[15])));
    rs += __shfl_xor(rs, 16);
    rs += __shfl_xor(rs, 32);
    l += rs;
#pragma unroll
    for (int nf = 0; nf < 4; ++nf){
      bf16x4v pk;
#pragma unroll
      for (int r = 0; r < 4; ++r) pk[r] = (__bf16)p[nf*4+r];
      *(bf16x4v*)(Pc + gofs + ((l15 * 128 + nf * 32 + lhi * 8) ^ swz)) = pk;
    }
    __builtin_amdgcn_s_setprio(1);
#pragma unroll
    for (int kk = 0; kk < 2; ++kk){
      const bf16x8 pa = *(const bf16x8*)(Pc + gofs + ((l15 * 128 + kk * 64 + lhi * 16) ^ swz));
#pragma unroll
      for (int df = 0; df < 4; ++df)
        o[df] = MFMA16(pa, vf[kk*4+df], o[df]);
    }
    __builtin_amdgcn_s_setprio(0);
  };

  for (int half = 0; half < 2; ++half){
    const int qt = (half == 0) ? (15 - bx) : bx;
    const int qr0 = qt * 128 + w * 32;

    bf16x8 qf[2][2];
#pragma unroll
    for (int g = 0; g < 2; ++g){
      qf[g][0] = *(const bf16x8*)&qp[(qr0 + g * 16 + l15) * 64 + lhi * 8];
      qf[g][1] = *(const bf16x8*)&qp[(qr0 + g * 16 + l15) * 64 + 32 + lhi * 8];
    }

    f32x4 o[2][4];
#pragma unroll
    for (int g = 0; g < 2; ++g)
#pragma unroll
      for (int df = 0; df < 4; ++df) o[g][df] = f32x4{0.f,0.f,0.f,0.f};
    float m[2] = {-1e30f, -1e30f}, l[2] = {0.f, 0.f};

    const int nStage = 2 * qt + 2;
    const int nC = 2 * qt + 1 + (w >> 1);
    int cur = 0;

    gload_lds16(kbytes + (size_t)srow * 128 + sch * 16,        (char*)Kbuf[0] + w * 1024);
    gload_lds16(kbytes + (size_t)(srow + 32) * 128 + sch * 16, (char*)Kbuf[0] + 4096 + w * 1024);
    gload_lds16(vbytes + (size_t)srow * 4096 + sch * 16,        (char*)Vbuf[0] + w * 1024);
    gload_lds16(vbytes + (size_t)(srow + 32) * 4096 + sch * 16, (char*)Vbuf[0] + 4096 + w * 1024);
    __syncthreads();

    for (int it = 0; it < nStage; ++it){
      const int jb = it * 64;
      if (it + 1 < nStage){
        const char* kb2 = kbytes + (size_t)(jb + 64) * 128;
        const char* vb2 = vbytes + (size_t)(jb + 64) * 2;
        char* kd = (char*)Kbuf[cur ^ 1];
        char* vd = (char*)Vbuf[cur ^ 1];
        gload_lds16(kb2 + (size_t)srow * 128 + sch * 16,        kd + w * 1024);
        gload_lds16(kb2 + (size_t)(srow + 32) * 128 + sch * 16, kd + 4096 + w * 1024);
        gload_lds16(vb2 + (size_t)srow * 4096 + sch * 16,        vd + w * 1024);
        gload_lds16(vb2 + (size_t)(srow + 32) * 4096 + sch * 16, vd + 4096 + w * 1024);
      }
      if (it < nC){
        const char* Kc = (const char*)Kbuf[cur];
        const char* Vc = (const char*)Vbuf[cur];
        bf16x8 kf[8];
#pragma unroll
        for (int nf = 0; nf < 4; ++nf)
#pragma unroll
          for (int kk = 0; kk < 2; ++kk)
            kf[2*nf+kk] = *(const bf16x8*)(Kc + (((nf * 16 + l15) * 128 + kk * 64 + lhi * 16) ^ swz));
        f32x4 s[2][4];
        __builtin_amdgcn_s_setprio(1);
#pragma unroll
        for (int g = 0; g < 2; ++g)
#pragma unroll
          for (int nf = 0; nf < 4; ++nf){
            f32x4 z = {0.f, 0.f, 0.f, 0.f};
            z = MFMA16(kf[2*nf], qf[g][0], z);
            z = MFMA16(kf[2*nf+1], qf[g][1], z);
            s[g][nf] = z;
          }
        __builtin_amdgcn_s_setprio(0);
        bf16x8 vf[8];
#pragma unroll
        for (int kk = 0; kk < 2; ++kk)
#pragma unroll
          for (int df = 0; df < 4; ++df)
            vf[kk*4+df] = *(const bf16x8*)(Vc + (((df * 16 + l15) * 128 + kk * 64 + lhi * 16) ^ swz));
        const bool domask = (it == nC - 1);
        process(s[0], m[0], l[0], o[0], vf, qr0,      domask, jb, 0);
        process(s[1], m[1], l[1], o[1], vf, qr0 + 16, domask, jb, 2048);
      }
      __syncthreads();
      cur ^= 1;
    }

#pragma unroll
    for (int g = 0; g < 2; ++g){
      const float linv = 1.0f / l[g];
      float lr[4];
#pragma unroll
      for (int r = 0; r < 4; ++r)
        lr[r] = __shfl(linv, (lane & 48) | (lhi * 4 + r));
#pragma unroll
      for (int r = 0; r < 4; ++r){
        const int qrow = qr0 + g * 16 + lhi * 4 + r;
#pragma unroll
        for (int df = 0; df < 4; ++df)
          a_bf[((size_t)b * 2048 + qrow) * 1024 + h * 64 + df * 16 + l15] = f2b(o[g][df][r] * lr[r]);
      }
    }
  }
}

extern "C" void kernel_launch(void* const* d_in, const int* in_sizes, int n_in,
                              void* d_out, int out_size, void* d_ws, size_t ws_size,
                              hipStream_t stream)
{
  const float* x      = (const float*)d_in[0];
  const float* w_attn = (const float*)d_in[1];
  const float* b_attn = (const float*)d_in[2];
  const float* w_proj = (const float*)d_in[3];
  const float* b_proj = (const float*)d_in[4];
  float* out = (float*)d_out;
  char* ws = (char*)d_ws;
  const size_t MB = 1u << 20;
  u16* x_bf  = (u16*)(ws + 0);        // 16 MB, reused as a_bf after attention
  u16* wA_T  = (u16*)(ws + 16 * MB);  // 6 MB
  u16* wP_T  = (u16*)(ws + 22 * MB);  // 2 MB
  u16* q_bf  = (u16*)(ws + 24 * MB);  // 16 MB
  u16* k_bf  = (u16*)(ws + 40 * MB);  // 16 MB
  u16* vT_bf = (u16*)(ws + 56 * MB);  // 16 MB
  u16* a_bf  = x_bf;

  cvt_bf16<<<dim3(8192), dim3(256), 0, stream>>>(x, x_bf, 4 * 2048 * 1024);
  transpose_cvt<<<dim3(96, 32), dim3(32, 8), 0, stream>>>(w_attn, wA_T, 1024, 3072);
  transpose_cvt<<<dim3(32, 32), dim3(32, 8), 0, stream>>>(w_proj, wP_T, 1024, 1024);
  gemm256_qkv<<<dim3(12, 32), dim3(512), 131072, stream>>>(
      x_bf, wA_T, b_attn, out, q_bf, k_bf, vT_bf);
  attn_kern<<<dim3(8, 64), dim3(256), 0, stream>>>(q_bf, k_bf, vT_bf, a_bf);
  gemm_proj<<<dim3(8, 64), dim3(256), 0, stream>>>(
      a_bf, wP_T, b_proj, out, 8192, 1024, 1024);
}

// Round 11
// 194.266 us; speedup vs baseline: 1.7086x; 1.0190x over previous
//
#include <hip/hip_runtime.h>
#include <stdint.h>

typedef unsigned short u16;
typedef __attribute__((ext_vector_type(8))) __bf16 bf16x8;
typedef __attribute__((ext_vector_type(4))) __bf16 bf16x4v;
typedef __attribute__((ext_vector_type(4))) float f32x4;
typedef __attribute__((ext_vector_type(4))) unsigned short u16x4;
typedef __attribute__((ext_vector_type(8))) unsigned short u16x8;

#define MFMA16(a,b,c) __builtin_amdgcn_mfma_f32_16x16x32_bf16(a,b,c,0,0,0)

// hardware v_exp_f32 (2^x)
static __device__ __forceinline__ float fexp2(float x){
#if __has_builtin(__builtin_amdgcn_exp2f)
  return __builtin_amdgcn_exp2f(x);
#else
  float r; asm("v_exp_f32 %0, %1" : "=v"(r) : "v"(x)); return r;
#endif
}

// f32 -> bf16 bits, round-to-nearest-even
static __device__ __forceinline__ u16 f2b(float f){
  uint32_t u = __float_as_uint(f);
  u += 0x7fffu + ((u >> 16) & 1u);
  return (u16)(u >> 16);
}

static __device__ __forceinline__ void gload_lds16(const void* g, void* l){
  __builtin_amdgcn_global_load_lds(
      (__attribute__((address_space(1))) void*)(uintptr_t)g,
      (__attribute__((address_space(3))) void*)(uintptr_t)l,
      16, 0, 0);
}

// ---------------- fp32 -> bf16 elementwise ----------------
__global__ __launch_bounds__(256) void cvt_bf16(const float* __restrict__ in,
                                                u16* __restrict__ out, int n){
  int i = (blockIdx.x * 256 + threadIdx.x) * 4;
  if (i >= n) return;
  float4 v = *(const float4*)(in + i);
  u16x4 o;
  o.x = f2b(v.x); o.y = f2b(v.y); o.z = f2b(v.z); o.w = f2b(v.w);
  *(u16x4*)(out + i) = o;
}

// ---------------- transpose+convert: in[K][N] f32 -> out[N][K] bf16 ----------------
__global__ __launch_bounds__(256) void transpose_cvt(const float* __restrict__ in,
                                                     u16* __restrict__ out,
                                                     int K, int N){
  __shared__ float tile[32][33];
  const int nb = blockIdx.x * 32, kb = blockIdx.y * 32;
  const int tx = threadIdx.x, ty = threadIdx.y; // (32,8)
#pragma unroll
  for (int i = 0; i < 32; i += 8)
    tile[ty + i][tx] = in[(size_t)(kb + ty + i) * N + nb + tx];
  __syncthreads();
#pragma unroll
  for (int i = 0; i < 32; i += 8)
    out[(size_t)(nb + ty + i) * K + kb + tx] = f2b(tile[tx][ty + i]);
}

// ---------------- pipelined GEMM: 256x128 tile, BK=32, 8 waves, 3-deep ring ----
// Counted-vmcnt: stage(kt) issued during kt-2 (3 loads/thread); at iter top
// vmcnt(3) (last: 0) -> tile kt complete; s_barrier. Ring write buf[(kt+2)%3]
// vs read buf[kt%3] disjoint; one barrier separates read(kt-1) from write
// issue into the same buffer. T2 16B-chunk XOR swizzle both sides.
// MODE 0: Cout[M,N] fp32 + bias.  MODE 1 (QKV): q/k LDS-retile -> b128
// stores; v packed along s; present fp32 direct.
template<int MODE>
__global__ __launch_bounds__(512, 2) void gemm_pipe(
    const u16* __restrict__ A, const u16* __restrict__ Bt,
    const float* __restrict__ bias, float* __restrict__ Cout,
    u16* __restrict__ q_bf, u16* __restrict__ k_bf, u16* __restrict__ vT_bf,
    int N, int K)
{
  extern __shared__ u16 smem[];      // 3 bufs x (A 16KB + B 8KB) = 72 KB
  const int nT = K >> 5;
  const int tid = threadIdx.x;
  const int w = tid >> 6, lane = tid & 63;
  const int l15 = lane & 15, lhi = lane >> 4;
  const int wr = w >> 1, wc = w & 1;           // 4M x 2N wave grid
  const int mBase = blockIdx.y * 256, nBase = blockIdx.x * 128;

  // staging: 16B chunks, 4 per 32-col row; source chunk pre-swizzled
  const int r0 = tid >> 2;                     // 0..127
  const int ch = (tid & 3) ^ (r0 & 3);
  const u16* Ag  = A  + (size_t)(mBase + r0) * K + ch * 8;
  const u16* Ag2 = Ag + (size_t)128 * K;
  const u16* Bg  = Bt + (size_t)(nBase + r0) * K + ch * 8;

  f32x4 acc[4][4];
#pragma unroll
  for (int i = 0; i < 4; ++i)
#pragma unroll
    for (int j = 0; j < 4; ++j) acc[i][j] = f32x4{0.f, 0.f, 0.f, 0.f};

  auto stage = [&](int kt){
    char* buf = (char*)smem + (kt % 3) * 24576;
    const int kb = kt << 5;
    gload_lds16(Ag  + kb, buf + tid * 16);
    gload_lds16(Ag2 + kb, buf + 8192 + tid * 16);
    gload_lds16(Bg  + kb, buf + 16384 + tid * 16);
  };

  stage(0); stage(1);

  for (int kt = 0; kt < nT; ++kt){
    if (kt == nT - 1) asm volatile("s_waitcnt vmcnt(0)" ::: "memory");
    else              asm volatile("s_waitcnt vmcnt(3)" ::: "memory");
    __builtin_amdgcn_s_barrier();
    const char* Ab = (const char*)smem + (kt % 3) * 24576;
    const char* Bb = Ab + 16384;
#define LDT(base, row) (*(const bf16x8*)((base) + ((row) << 6) + (((lhi ^ ((row) & 3))) << 4)))
    bf16x8 a0, a1, a2, a3, b0, b1, b2, b3;
    {
      const int ar = wr * 64 + l15;
      a0 = LDT(Ab, ar); a1 = LDT(Ab, ar + 16); a2 = LDT(Ab, ar + 32); a3 = LDT(Ab, ar + 48);
      const int br = wc * 64 + l15;
      b0 = LDT(Bb, br); b1 = LDT(Bb, br + 16); b2 = LDT(Bb, br + 32); b3 = LDT(Bb, br + 48);
    }
#undef LDT
    if (kt + 2 < nT) stage(kt + 2);
    __builtin_amdgcn_s_setprio(1);
    acc[0][0] = MFMA16(a0, b0, acc[0][0]); acc[0][1] = MFMA16(a0, b1, acc[0][1]);
    acc[0][2] = MFMA16(a0, b2, acc[0][2]); acc[0][3] = MFMA16(a0, b3, acc[0][3]);
    acc[1][0] = MFMA16(a1, b0, acc[1][0]); acc[1][1] = MFMA16(a1, b1, acc[1][1]);
    acc[1][2] = MFMA16(a1, b2, acc[1][2]); acc[1][3] = MFMA16(a1, b3, acc[1][3]);
    acc[2][0] = MFMA16(a2, b0, acc[2][0]); acc[2][1] = MFMA16(a2, b1, acc[2][1]);
    acc[2][2] = MFMA16(a2, b2, acc[2][2]); acc[2][3] = MFMA16(a2, b3, acc[2][3]);
    acc[3][0] = MFMA16(a3, b0, acc[3][0]); acc[3][1] = MFMA16(a3, b1, acc[3][1]);
    acc[3][2] = MFMA16(a3, b2, acc[3][2]); acc[3][3] = MFMA16(a3, b3, acc[3][3]);
    __builtin_amdgcn_s_setprio(0);
  }

  // ---------------- epilogue ----------------
  if (MODE == 0){
#pragma unroll
    for (int ni = 0; ni < 4; ++ni){
      const int col = nBase + wc * 64 + ni * 16 + l15;
      const float bv = bias[col];
#pragma unroll
      for (int mi = 0; mi < 4; ++mi)
#pragma unroll
        for (int r = 0; r < 4; ++r){
          const int row = mBase + wr * 64 + mi * 16 + lhi * 4 + r;
          Cout[(size_t)row * N + col] = acc[mi][ni][r] + bv;
        }
    }
    return;
  }

  const int sec = nBase >> 10;          // 0=q, 1=k, 2=v (128 | 1024)
  const int nn0 = nBase & 1023;
  const int bb_ = mBase >> 11;
  const int s0  = mBase & 2047;

  if (sec == 2){
#pragma unroll
    for (int ni = 0; ni < 4; ++ni){
      const int c = wc * 64 + ni * 16 + l15;
      const int nn = nn0 + c;
      const int h = nn >> 6, d = nn & 63;
      const float bv = bias[nBase + c];
#pragma unroll
      for (int mi = 0; mi < 4; ++mi){
        const int sb = s0 + wr * 64 + mi * 16 + lhi * 4;
        u16x4 pk;
#pragma unroll
        for (int r = 0; r < 4; ++r){
          const float v = acc[mi][ni][r] + bv;
          pk[r] = f2b(v);
          Cout[16777216 + ((size_t)(bb_ * 16 + h) * 2048 + sb + r) * 64 + d] = v;
        }
        *(u16x4*)(vT_bf + ((size_t)(bb_ * 16 + h) * 64 + d) * 2048 + sb) = pk;
      }
    }
    return;
  }

  // q or k: retile through LDS (256x128 bf16, 8-u16 XOR swizzle), b128 stores
  __syncthreads();   // all waves done reading ring buffers
  const float qscl = (sec == 0) ? 0.1803368801111204f : 1.0f;
#pragma unroll
  for (int ni = 0; ni < 4; ++ni){
    const int c = wc * 64 + ni * 16 + l15;
    const float bv = bias[nBase + c];
#pragma unroll
    for (int mi = 0; mi < 4; ++mi)
#pragma unroll
      for (int r = 0; r < 4; ++r){
        const int rl = wr * 64 + mi * 16 + lhi * 4 + r;
        smem[rl * 128 + (c ^ ((rl & 7) << 3))] = f2b((acc[mi][ni][r] + bv) * qscl);
      }
  }
  if (sec == 1){
#pragma unroll
    for (int ni = 0; ni < 4; ++ni){
      const int c = wc * 64 + ni * 16 + l15;
      const int nn = nn0 + c;
      const int h = nn >> 6, d = nn & 63;
      const float bv = bias[nBase + c];
#pragma unroll
      for (int mi = 0; mi < 4; ++mi)
#pragma unroll
        for (int r = 0; r < 4; ++r){
          const int s = s0 + wr * 64 + mi * 16 + lhi * 4 + r;
          Cout[8388608 + ((size_t)(bb_ * 16 + h) * 2048 + s) * 64 + d] = acc[mi][ni][r] + bv;
        }
    }
  }
  __syncthreads();
  {
    const int row = tid >> 1, half = tid & 1;
    u16* base = (sec == 0 ? q_bf : k_bf);
#pragma unroll
    for (int i = 0; i < 8; ++i){
      const int c0 = half * 64 + i * 8;
      const int h = (nn0 >> 6) + (c0 >> 6);
      u16x8 vv = *(const u16x8*)&smem[row * 128 + (c0 ^ ((row & 7) << 3))];
      *(u16x8*)(base + ((size_t)(bb_ * 16 + h) * 2048 + s0 + row) * 64 + (c0 & 63)) = vv;
    }
  }
}

// ---------------- causal flash attention (unchanged from round 8) ----------------
__global__ __launch_bounds__(256) void attn_kern(
    const u16* __restrict__ q_bf, const u16* __restrict__ k_bf,
    const u16* __restrict__ vT_bf, u16* __restrict__ a_bf)
{
  const int S = 2048;
  const int id = (int)blockIdx.x + 8 * (int)blockIdx.y;
  const int xcd = id & 7, j = id >> 3;
  const int bh = xcd + 8 * (j & 7);
  const int bx = j >> 3;

  const int tid = threadIdx.x, w = tid >> 6, lane = tid & 63;
  const int l15 = lane & 15, lhi = lane >> 4;
  const u16* qp = q_bf + (size_t)bh * S * 64;
  const char* kbytes = (const char*)(k_bf + (size_t)bh * S * 64);
  const char* vbytes = (const char*)(vT_bf + (size_t)bh * 64 * S);
  const int b = bh >> 4, h = bh & 15;

  __shared__ u16 Kbuf[2][64 * 64];
  __shared__ u16 Vbuf[2][64 * 64];
  __shared__ u16 P_all[4][32 * 64];
  char* Pc = (char*)&P_all[w][0];
  const int swz = (l15 & 7) << 4;

  const int srow = tid >> 3;
  const int sch  = (tid & 7) ^ (srow & 7);

  auto process = [&](f32x4 (&s)[4], float &m, float &l, f32x4 (&o)[4],
                     const bf16x8 (&vf)[8], int qr0g, bool domask, int jb, int gofs){
    if (domask){
      const int q = qr0g + l15;
#pragma unroll
      for (int nf = 0; nf < 4; ++nf)
#pragma unroll
        for (int r = 0; r < 4; ++r){
          const int kv = jb + nf * 16 + lhi * 4 + r;
          if (kv > q) s[nf][r] = -1e10f;
        }
    }
    float a0 = fmaxf(s[0][0], s[0][1]), a1 = fmaxf(s[0][2], s[0][3]);
    float a2 = fmaxf(s[1][0], s[1][1]), a3 = fmaxf(s[1][2], s[1][3]);
    float a4 = fmaxf(s[2][0], s[2][1]), a5 = fmaxf(s[2][2], s[2][3]);
    float a6 = fmaxf(s[3][0], s[3][1]), a7 = fmaxf(s[3][2], s[3][3]);
    float x = fmaxf(fmaxf(fmaxf(a0,a1), fmaxf(a2,a3)),
                    fmaxf(fmaxf(a4,a5), fmaxf(a6,a7)));
    x = fmaxf(x, __shfl_xor(x, 16));
    x = fmaxf(x, __shfl_xor(x, 32));
    if (__any(x - m > 8.0f)){
      const float mn = fmaxf(m, x);
      const float sc = fexp2(m - mn);
      m = mn;
      l *= sc;
      float scq[4];
#pragma unroll
      for (int r = 0; r < 4; ++r)
        scq[r] = __shfl(sc, (lane & 48) | (lhi * 4 + r));
#pragma unroll
      for (int df = 0; df < 4; ++df)
#pragma unroll
        for (int r = 0; r < 4; ++r) o[df][r] *= scq[r];
    }
    float p[16];
#pragma unroll
    for (int nf = 0; nf < 4; ++nf)
#pragma unroll
      for (int r = 0; r < 4; ++r) p[nf*4+r] = fexp2(s[nf][r] - m);
    float rs = (((p[0]+p[1])+(p[2]+p[3])) + ((p[4]+p[5])+(p[6]+p[7])))
             + (((p[8]+p[9])+(p[10]+p[11])) + ((p[12]+p[13])+(p[14]+p[15])));
    rs += __shfl_xor(rs, 16);
    rs += __shfl_xor(rs, 32);
    l += rs;
#pragma unroll
    for (int nf = 0; nf < 4; ++nf){
      bf16x4v pk;
#pragma unroll
      for (int r = 0; r < 4; ++r) pk[r] = (__bf16)p[nf*4+r];
      *(bf16x4v*)(Pc + gofs + ((l15 * 128 + nf * 32 + lhi * 8) ^ swz)) = pk;
    }
    __builtin_amdgcn_s_setprio(1);
#pragma unroll
    for (int kk = 0; kk < 2; ++kk){
      const bf16x8 pa = *(const bf16x8*)(Pc + gofs + ((l15 * 128 + kk * 64 + lhi * 16) ^ swz));
#pragma unroll
      for (int df = 0; df < 4; ++df)
        o[df] = MFMA16(pa, vf[kk*4+df], o[df]);
    }
    __builtin_amdgcn_s_setprio(0);
  };

  for (int half = 0; half < 2; ++half){
    const int qt = (half == 0) ? (15 - bx) : bx;
    const int qr0 = qt * 128 + w * 32;

    bf16x8 qf[2][2];
#pragma unroll
    for (int g = 0; g < 2; ++g){
      qf[g][0] = *(const bf16x8*)&qp[(qr0 + g * 16 + l15) * 64 + lhi * 8];
      qf[g][1] = *(const bf16x8*)&qp[(qr0 + g * 16 + l15) * 64 + 32 + lhi * 8];
    }

    f32x4 o[2][4];
#pragma unroll
    for (int g = 0; g < 2; ++g)
#pragma unroll
      for (int df = 0; df < 4; ++df) o[g][df] = f32x4{0.f,0.f,0.f,0.f};
    float m[2] = {-1e30f, -1e30f}, l[2] = {0.f, 0.f};

    const int nStage = 2 * qt + 2;
    const int nC = 2 * qt + 1 + (w >> 1);
    int cur = 0;

    gload_lds16(kbytes + (size_t)srow * 128 + sch * 16,        (char*)Kbuf[0] + w * 1024);
    gload_lds16(kbytes + (size_t)(srow + 32) * 128 + sch * 16, (char*)Kbuf[0] + 4096 + w * 1024);
    gload_lds16(vbytes + (size_t)srow * 4096 + sch * 16,        (char*)Vbuf[0] + w * 1024);
    gload_lds16(vbytes + (size_t)(srow + 32) * 4096 + sch * 16, (char*)Vbuf[0] + 4096 + w * 1024);
    __syncthreads();

    for (int it = 0; it < nStage; ++it){
      const int jb = it * 64;
      if (it + 1 < nStage){
        const char* kb2 = kbytes + (size_t)(jb + 64) * 128;
        const char* vb2 = vbytes + (size_t)(jb + 64) * 2;
        char* kd = (char*)Kbuf[cur ^ 1];
        char* vd = (char*)Vbuf[cur ^ 1];
        gload_lds16(kb2 + (size_t)srow * 128 + sch * 16,        kd + w * 1024);
        gload_lds16(kb2 + (size_t)(srow + 32) * 128 + sch * 16, kd + 4096 + w * 1024);
        gload_lds16(vb2 + (size_t)srow * 4096 + sch * 16,        vd + w * 1024);
        gload_lds16(vb2 + (size_t)(srow + 32) * 4096 + sch * 16, vd + 4096 + w * 1024);
      }
      if (it < nC){
        const char* Kc = (const char*)Kbuf[cur];
        const char* Vc = (const char*)Vbuf[cur];
        bf16x8 kf[8];
#pragma unroll
        for (int nf = 0; nf < 4; ++nf)
#pragma unroll
          for (int kk = 0; kk < 2; ++kk)
            kf[2*nf+kk] = *(const bf16x8*)(Kc + (((nf * 16 + l15) * 128 + kk * 64 + lhi * 16) ^ swz));
        f32x4 s[2][4];
        __builtin_amdgcn_s_setprio(1);
#pragma unroll
        for (int g = 0; g < 2; ++g)
#pragma unroll
          for (int nf = 0; nf < 4; ++nf){
            f32x4 z = {0.f, 0.f, 0.f, 0.f};
            z = MFMA16(kf[2*nf], qf[g][0], z);
            z = MFMA16(kf[2*nf+1], qf[g][1], z);
            s[g][nf] = z;
          }
        __builtin_amdgcn_s_setprio(0);
        bf16x8 vf[8];
#pragma unroll
        for (int kk = 0; kk < 2; ++kk)
#pragma unroll
          for (int df = 0; df < 4; ++df)
            vf[kk*4+df] = *(const bf16x8*)(Vc + (((df * 16 + l15) * 128 + kk * 64 + lhi * 16) ^ swz));
        const bool domask = (it == nC - 1);
        process(s[0], m[0], l[0], o[0], vf, qr0,      domask, jb, 0);
        process(s[1], m[1], l[1], o[1], vf, qr0 + 16, domask, jb, 2048);
      }
      __syncthreads();
      cur ^= 1;
    }

#pragma unroll
    for (int g = 0; g < 2; ++g){
      const float linv = 1.0f / l[g];
      float lr[4];
#pragma unroll
      for (int r = 0; r < 4; ++r)
        lr[r] = __shfl(linv, (lane & 48) | (lhi * 4 + r));
#pragma unroll
      for (int r = 0; r < 4; ++r){
        const int qrow = qr0 + g * 16 + lhi * 4 + r;
#pragma unroll
        for (int df = 0; df < 4; ++df)
          a_bf[((size_t)b * 2048 + qrow) * 1024 + h * 64 + df * 16 + l15] = f2b(o[g][df][r] * lr[r]);
      }
    }
  }
}

extern "C" void kernel_launch(void* const* d_in, const int* in_sizes, int n_in,
                              void* d_out, int out_size, void* d_ws, size_t ws_size,
                              hipStream_t stream)
{
  const float* x      = (const float*)d_in[0];
  const float* w_attn = (const float*)d_in[1];
  const float* b_attn = (const float*)d_in[2];
  const float* w_proj = (const float*)d_in[3];
  const float* b_proj = (const float*)d_in[4];
  float* out = (float*)d_out;
  char* ws = (char*)d_ws;
  const size_t MB = 1u << 20;
  u16* x_bf  = (u16*)(ws + 0);        // 16 MB, reused as a_bf after attention
  u16* wA_T  = (u16*)(ws + 16 * MB);  // 6 MB
  u16* wP_T  = (u16*)(ws + 22 * MB);  // 2 MB
  u16* q_bf  = (u16*)(ws + 24 * MB);  // 16 MB
  u16* k_bf  = (u16*)(ws + 40 * MB);  // 16 MB
  u16* vT_bf = (u16*)(ws + 56 * MB);  // 16 MB
  u16* a_bf  = x_bf;

  cvt_bf16<<<dim3(8192), dim3(256), 0, stream>>>(x, x_bf, 4 * 2048 * 1024);
  transpose_cvt<<<dim3(96, 32), dim3(32, 8), 0, stream>>>(w_attn, wA_T, 1024, 3072);
  transpose_cvt<<<dim3(32, 32), dim3(32, 8), 0, stream>>>(w_proj, wP_T, 1024, 1024);
  gemm_pipe<1><<<dim3(24, 32), dim3(512), 73728, stream>>>(
      x_bf, wA_T, b_attn, out, q_bf, k_bf, vT_bf, 3072, 1024);
  attn_kern<<<dim3(8, 64), dim3(256), 0, stream>>>(q_bf, k_bf, vT_bf, a_bf);
  gemm_pipe<0><<<dim3(8, 32), dim3(512), 73728, stream>>>(
      a_bf, wP_T, b_proj, out, nullptr, nullptr, nullptr, 1024, 1024);
}